// Round 1
// baseline (2699.363 us; speedup 1.0000x reference)
//
#include <hip/hip_runtime.h>
#include <hip/hip_bf16.h>
#include <math.h>

#define N_TOK 4096
#define HID   2048
#define NH    16
#define HD    128
#define SEQ   1024
#define NSEQ  4
#define QKVN  (3*HID)   // 6144

// ---------------- GEMM: C[M][N] = A[M][K] * B[N][K]^T (fp32) ----------------
// 64x64 tile, BK=32, 256 threads, 4x4 micro-tile per thread.
template<int BK>
__global__ __launch_bounds__(256)
void gemm_nt(const float* __restrict__ A, const float* __restrict__ B,
             float* __restrict__ C, int M, int N, int K) {
  constexpr int BM = 64, BN = 64;
  __shared__ float As[BK][BM];   // stored transposed: As[k][m]
  __shared__ float Bs[BK][BN];   // Bs[k][n]
  const int m0 = blockIdx.y * BM, n0 = blockIdx.x * BN;
  const int tid = threadIdx.x;
  const int tm = tid >> 4, tn = tid & 15;      // 16x16 thread grid
  const int ar = tid >> 2;                     // staging row 0..63
  const int ak = (tid & 3) * 8;                // staging k-group
  const float* Aptr = A + (size_t)(m0 + ar) * K + ak;
  const float* Bptr = B + (size_t)(n0 + ar) * K + ak;
  float acc[4][4] = {};
  for (int k0 = 0; k0 < K; k0 += BK) {
    float4 a0 = *(const float4*)(Aptr + k0);
    float4 a1 = *(const float4*)(Aptr + k0 + 4);
    float4 b0 = *(const float4*)(Bptr + k0);
    float4 b1 = *(const float4*)(Bptr + k0 + 4);
    __syncthreads();   // previous iteration done reading LDS
    As[ak+0][ar] = a0.x; As[ak+1][ar] = a0.y; As[ak+2][ar] = a0.z; As[ak+3][ar] = a0.w;
    As[ak+4][ar] = a1.x; As[ak+5][ar] = a1.y; As[ak+6][ar] = a1.z; As[ak+7][ar] = a1.w;
    Bs[ak+0][ar] = b0.x; Bs[ak+1][ar] = b0.y; Bs[ak+2][ar] = b0.z; Bs[ak+3][ar] = b0.w;
    Bs[ak+4][ar] = b1.x; Bs[ak+5][ar] = b1.y; Bs[ak+6][ar] = b1.z; Bs[ak+7][ar] = b1.w;
    __syncthreads();
    #pragma unroll
    for (int kk = 0; kk < BK; ++kk) {
      float4 av = *(const float4*)&As[kk][tm * 4];
      float4 bv = *(const float4*)&Bs[kk][tn * 4];
      float a_[4] = {av.x, av.y, av.z, av.w};
      float b_[4] = {bv.x, bv.y, bv.z, bv.w};
      #pragma unroll
      for (int i = 0; i < 4; ++i)
        #pragma unroll
        for (int j = 0; j < 4; ++j)
          acc[i][j] = fmaf(a_[i], b_[j], acc[i][j]);
    }
  }
  #pragma unroll
  for (int i = 0; i < 4; ++i) {
    float4 o = make_float4(acc[i][0], acc[i][1], acc[i][2], acc[i][3]);
    *(float4*)&C[(size_t)(m0 + tm * 4 + i) * N + n0 + tn * 4] = o;
  }
}

// ---------------- RoPE + RMSNorm, in place on q and k parts of qkv ----------
// One wave per (token, {q,k}, head). Lane d handles the (d, d+64) rotation pair.
__global__ __launch_bounds__(256)
void rope_rms(float* __restrict__ qkv, const float* __restrict__ norm_w,
              const float* __restrict__ cosc, const float* __restrict__ sinc,
              const int* __restrict__ cu) {
  const int wid  = blockIdx.x * 4 + (threadIdx.x >> 6);
  const int lane = threadIdx.x & 63;
  const int t   = wid >> 5;       // 32 waves per token (2 tensors x 16 heads)
  const int rem = wid & 31;
  const int s   = rem >> 4;       // 0=q, 1=k
  const int h   = rem & 15;
  const int b   = t >> 10;        // SEQ = 1024
  const int pos = t - cu[b];
  float* p = qkv + (size_t)t * QKVN + s * HID + h * HD;
  float x1 = p[lane], x2 = p[lane + 64];
  float c  = cosc[pos * 64 + lane];
  float sn = sinc[pos * 64 + lane];
  float y1 = x1 * c + x2 * sn;
  float y2 = x2 * c - x1 * sn;
  float ss = y1 * y1 + y2 * y2;
  #pragma unroll
  for (int o = 32; o > 0; o >>= 1) ss += __shfl_xor(ss, o, 64);
  float r = rsqrtf(ss * (1.0f / 128.0f) + 1e-6f);
  p[lane]      = y1 * r * norm_w[lane];
  p[lane + 64] = y2 * r * norm_w[lane + 64];
}

// ---------------- gate = sigmoid(x @ gate_w^T + gate_b), [N_TOK][NH] --------
__global__ __launch_bounds__(256)
void gate_kernel(const float* __restrict__ x, const float* __restrict__ gw,
                 const float* __restrict__ gb, float* __restrict__ gate) {
  __shared__ float xs[HID];
  const int t = blockIdx.x, tid = threadIdx.x;
  *(float4*)&xs[tid * 8]     = *(const float4*)&x[(size_t)t * HID + tid * 8];
  *(float4*)&xs[tid * 8 + 4] = *(const float4*)&x[(size_t)t * HID + tid * 8 + 4];
  __syncthreads();
  const int h = tid >> 4, i = tid & 15;
  const float* w  = gw + (size_t)h * HID + i * 128;
  const float* xx = xs + i * 128;
  float sum = 0.f;
  #pragma unroll
  for (int j = 0; j < 128; j += 4) {
    float4 wv = *(const float4*)(w + j);
    float4 xv = *(const float4*)(xx + j);
    sum += wv.x * xv.x + wv.y * xv.y + wv.z * xv.z + wv.w * xv.w;
  }
  sum += __shfl_xor(sum, 8, 64);
  sum += __shfl_xor(sum, 4, 64);
  sum += __shfl_xor(sum, 2, 64);
  sum += __shfl_xor(sum, 1, 64);
  if (i == 0) gate[t * NH + h] = 1.f / (1.f + __expf(-(sum + gb[h])));
}

// ---------------- causal flash attention, fp32, gate fused in epilogue ------
// grid.x = b*NH+h (64), grid.y = q tile (16). 256 threads, 64-row Q tile.
__global__ __launch_bounds__(256)
void attn_kernel(const float* __restrict__ qkv, const float* __restrict__ gate,
                 float* __restrict__ og) {
  constexpr int PADD = HD + 4;   // row stride 132 floats: odd multiple of 16B
  constexpr int PS   = 65;
  __shared__ float Qs[64][PADD];
  __shared__ float Ks[64][PADD];
  __shared__ float Vs[64][PADD];
  __shared__ float Ps[64][PS];
  const int bh = blockIdx.x, b = bh >> 4, h = bh & 15;
  const int qt = blockIdx.y;
  const int tid = threadIdx.x;
  const float scale = 0.08838834764831845f;  // 1/sqrt(128)
  const float* base = qkv + (size_t)b * SEQ * QKVN + h * HD;
  const float* qb = base;
  const float* kb = base + HID;
  const float* vb = base + 2 * HID;
  // load + pre-scale Q tile
  {
    const int r = tid >> 2, cg = (tid & 3) * 32;
    const float* src = qb + (size_t)(qt * 64 + r) * QKVN + cg;
    #pragma unroll
    for (int j = 0; j < 32; j += 4) {
      float4 v = *(const float4*)(src + j);
      v.x *= scale; v.y *= scale; v.z *= scale; v.w *= scale;
      *(float4*)&Qs[r][cg + j] = v;
    }
  }
  float O[32] = {};
  float m_run = -INFINITY, l_run = 0.f;
  const int orow = tid >> 2, oi = tid & 3;   // O ownership: row, col-group
  const int tr = tid >> 4, tc = tid & 15;    // score ownership
  for (int kt = 0; kt <= qt; ++kt) {
    __syncthreads();   // prev iteration done with Ks/Vs/Ps
    {
      const int r = tid >> 2, cg = (tid & 3) * 32;
      const float* ksrc = kb + (size_t)(kt * 64 + r) * QKVN + cg;
      const float* vsrc = vb + (size_t)(kt * 64 + r) * QKVN + cg;
      #pragma unroll
      for (int j = 0; j < 32; j += 4) {
        *(float4*)&Ks[r][cg + j] = *(const float4*)(ksrc + j);
        *(float4*)&Vs[r][cg + j] = *(const float4*)(vsrc + j);
      }
    }
    __syncthreads();
    // S = Q K^T : rows 4*tr..+3, cols tc+16j (col interleave avoids LDS conflicts)
    float s[4][4] = {};
    #pragma unroll
    for (int k4 = 0; k4 < HD / 4; ++k4) {
      float4 q_[4], k_[4];
      #pragma unroll
      for (int i = 0; i < 4; ++i) q_[i] = *(const float4*)&Qs[tr * 4 + i][k4 * 4];
      #pragma unroll
      for (int j = 0; j < 4; ++j) k_[j] = *(const float4*)&Ks[tc + 16 * j][k4 * 4];
      #pragma unroll
      for (int i = 0; i < 4; ++i)
        #pragma unroll
        for (int j = 0; j < 4; ++j)
          s[i][j] += q_[i].x * k_[j].x + q_[i].y * k_[j].y +
                     q_[i].z * k_[j].z + q_[i].w * k_[j].w;
    }
    if (kt == qt) {
      #pragma unroll
      for (int i = 0; i < 4; ++i)
        #pragma unroll
        for (int j = 0; j < 4; ++j)
          if (tc + 16 * j > tr * 4 + i) s[i][j] = -INFINITY;
    }
    #pragma unroll
    for (int i = 0; i < 4; ++i)
      #pragma unroll
      for (int j = 0; j < 4; ++j)
        Ps[tr * 4 + i][tc + 16 * j] = s[i][j];
    __syncthreads();
    // online softmax: 4 threads per row, each scans 16 cols
    {
      const int r = orow, seg = oi * 16;
      float mx = -INFINITY;
      #pragma unroll
      for (int j = 0; j < 16; ++j) mx = fmaxf(mx, Ps[r][seg + j]);
      mx = fmaxf(mx, __shfl_xor(mx, 1, 64));
      mx = fmaxf(mx, __shfl_xor(mx, 2, 64));
      float mnew = fmaxf(m_run, mx);
      float corr = __expf(m_run - mnew);   // exp(-inf)=0 on first tile
      float ls = 0.f;
      #pragma unroll
      for (int j = 0; j < 16; ++j) {
        float pv = __expf(Ps[r][seg + j] - mnew);
        Ps[r][seg + j] = pv;
        ls += pv;
      }
      ls += __shfl_xor(ls, 1, 64);
      ls += __shfl_xor(ls, 2, 64);
      l_run = l_run * corr + ls;
      m_run = mnew;
      #pragma unroll
      for (int c = 0; c < 32; ++c) O[c] *= corr;
    }
    __syncthreads();
    // O += P V : thread owns row orow, cols {c4*16 + oi*4 .. +3}
    #pragma unroll 4
    for (int j = 0; j < 64; ++j) {
      float pv = Ps[orow][j];
      #pragma unroll
      for (int c4 = 0; c4 < 8; ++c4) {
        float4 vv = *(const float4*)&Vs[j][c4 * 16 + oi * 4];
        O[c4 * 4 + 0] = fmaf(pv, vv.x, O[c4 * 4 + 0]);
        O[c4 * 4 + 1] = fmaf(pv, vv.y, O[c4 * 4 + 1]);
        O[c4 * 4 + 2] = fmaf(pv, vv.z, O[c4 * 4 + 2]);
        O[c4 * 4 + 3] = fmaf(pv, vv.w, O[c4 * 4 + 3]);
      }
    }
  }
  // epilogue: 1/l, gate, store
  {
    const int t = b * SEQ + qt * 64 + orow;
    const float g = gate[t * NH + h];
    const float inv = g / l_run;
    float* dst = og + (size_t)t * HID + h * HD;
    #pragma unroll
    for (int c4 = 0; c4 < 8; ++c4) {
      float4 o4 = make_float4(O[c4 * 4 + 0] * inv, O[c4 * 4 + 1] * inv,
                              O[c4 * 4 + 2] * inv, O[c4 * 4 + 3] * inv);
      *(float4*)&dst[c4 * 16 + oi * 4] = o4;
    }
  }
}

extern "C" void kernel_launch(void* const* d_in, const int* in_sizes, int n_in,
                              void* d_out, int out_size, void* d_ws, size_t ws_size,
                              hipStream_t stream) {
  const float* x    = (const float*)d_in[0];
  const float* Wqkv = (const float*)d_in[1];
  const float* Wo   = (const float*)d_in[2];
  const float* gw   = (const float*)d_in[3];
  const float* gb   = (const float*)d_in[4];
  const float* nw   = (const float*)d_in[5];
  const float* cosc = (const float*)d_in[6];
  const float* sinc = (const float*)d_in[7];
  const int*   cu   = (const int*)d_in[8];
  float* out = (float*)d_out;

  float* qkv  = (float*)d_ws;                       // [N_TOK][3*HID]  100.7 MB
  float* attn = qkv + (size_t)N_TOK * QKVN;         // [N_TOK][HID]     33.6 MB
  float* gate = attn + (size_t)N_TOK * HID;         // [N_TOK][NH]      0.26 MB

  gemm_nt<32><<<dim3(QKVN / 64, N_TOK / 64), 256, 0, stream>>>(x, Wqkv, qkv, N_TOK, QKVN, HID);
  rope_rms<<<dim3(N_TOK * 2 * NH / 4), 256, 0, stream>>>(qkv, nw, cosc, sinc, cu);
  gate_kernel<<<dim3(N_TOK), 256, 0, stream>>>(x, gw, gb, gate);
  attn_kernel<<<dim3(NSEQ * NH, SEQ / 64), 256, 0, stream>>>(qkv, gate, attn);
  gemm_nt<32><<<dim3(HID / 64, N_TOK / 64), 256, 0, stream>>>(attn, Wo, out, N_TOK, HID, HID);
}

// Round 2
// 1439.324 us; speedup vs baseline: 1.8754x; 1.8754x over previous
//
#include <hip/hip_runtime.h>
#include <hip/hip_bf16.h>
#include <math.h>

#define N_TOK 4096
#define HID   2048
#define NH    16
#define HD    128
#define SEQ   1024
#define NSEQ  4
#define QKVN  (3*HID)   // 6144
#define KSPLIT (3*HID)  // split-K width: [hi|hi|lo] x [hi|lo|hi]

typedef __bf16 bf16x8 __attribute__((ext_vector_type(8)));
typedef float  f32x4  __attribute__((ext_vector_type(4)));

__device__ __forceinline__ ushort bf16_rn(float f) {
  unsigned u = __float_as_uint(f);
  return (ushort)((u + 0x7FFFu + ((u >> 16) & 1u)) >> 16);
}
__device__ __forceinline__ float bf16_tof(ushort h) {
  return __uint_as_float(((unsigned)h) << 16);
}

__device__ __forceinline__ void gload16(const void* g, void* l) {
  __builtin_amdgcn_global_load_lds(
      (const __attribute__((address_space(1))) void*)g,
      (__attribute__((address_space(3))) void*)l, 16, 0, 0);
}

// ---- split fp32 [R][2048] -> bf16 [R][6144] as [hi | X | Y] ----------------
// amode=1 (A operand): X=hi, Y=lo.  amode=0 (B operand): X=lo, Y=hi.
__global__ __launch_bounds__(256)
void split_bf16(const float* __restrict__ src, ushort* __restrict__ dst,
                int total4, int amode) {
  for (int idx = blockIdx.x * 256 + threadIdx.x; idx < total4;
       idx += gridDim.x * 256) {
    const int r = idx >> 9, kq = idx & 511;   // K=2048 -> 512 float4 per row
    float4 v = ((const float4*)src)[idx];
    float f[4] = {v.x, v.y, v.z, v.w};
    ushort h[4], lo[4];
    #pragma unroll
    for (int j = 0; j < 4; ++j) {
      h[j]  = bf16_rn(f[j]);
      lo[j] = bf16_rn(f[j] - bf16_tof(h[j]));
    }
    ushort4 hv = make_ushort4(h[0], h[1], h[2], h[3]);
    ushort4 lv = make_ushort4(lo[0], lo[1], lo[2], lo[3]);
    ushort* row = dst + (size_t)r * KSPLIT + kq * 4;
    *(ushort4*)(row)        = hv;
    *(ushort4*)(row + 2048) = amode ? hv : lv;
    *(ushort4*)(row + 4096) = amode ? lv : hv;
  }
}

// ---- bf16 MFMA GEMM: C[M][N] f32 = A[M][K] * B[N][K]^T  (m97 structure) ----
// 128x128 tile, BK=32, 256 threads = 4 waves (2x2), 4x4 16x16x32 frags/wave.
__global__ __launch_bounds__(256)
void gemm_bf16_nt(const ushort* __restrict__ A, const ushort* __restrict__ B,
                  float* __restrict__ C, int M, int N, int K) {
  __shared__ ushort As[128 * 32];   // [row][k] linear (global_load_lds dest)
  __shared__ ushort Bs[128 * 32];
  const int tid = threadIdx.x;
  const int w = tid >> 6, l = tid & 63;
  const int wm = w >> 1, wn = w & 1;
  const int m0 = blockIdx.y * 128, n0 = blockIdx.x * 128;
  const int lr = l & 15;            // fragment row
  const int ko = (l >> 4) * 8;      // fragment k-offset (elems)
  const int srow = l >> 2;          // staging: lane's row within 16-row chunk
  const int scol = (l & 3) * 8;     // staging: lane's k-offset (elems)

  f32x4 acc[4][4];
  #pragma unroll
  for (int m = 0; m < 4; ++m)
    #pragma unroll
    for (int n = 0; n < 4; ++n)
      acc[m][n] = (f32x4){0.f, 0.f, 0.f, 0.f};

  for (int k0 = 0; k0 < K; k0 += 32) {
    #pragma unroll
    for (int i = 0; i < 2; ++i) {
      const int rbase = w * 32 + i * 16;   // wave-uniform
      const ushort* ga = A + (size_t)(m0 + rbase + srow) * K + k0 + scol;
      const ushort* gb = B + (size_t)(n0 + rbase + srow) * K + k0 + scol;
      gload16(ga, &As[rbase * 32]);
      gload16(gb, &Bs[rbase * 32]);
    }
    __syncthreads();   // drains vmcnt before barrier (compiler-inserted)
    bf16x8 av[4], bv[4];
    #pragma unroll
    for (int m = 0; m < 4; ++m)
      av[m] = *(const bf16x8*)&As[(wm * 64 + m * 16 + lr) * 32 + ko];
    #pragma unroll
    for (int n = 0; n < 4; ++n)
      bv[n] = *(const bf16x8*)&Bs[(wn * 64 + n * 16 + lr) * 32 + ko];
    #pragma unroll
    for (int m = 0; m < 4; ++m)
      #pragma unroll
      for (int n = 0; n < 4; ++n)
        acc[m][n] = __builtin_amdgcn_mfma_f32_16x16x32_bf16(av[m], bv[n],
                                                            acc[m][n], 0, 0, 0);
    __syncthreads();   // LDS reads done before next stage overwrites
  }
  // C/D layout (m89/m91): col = lane&15, row = (lane>>4)*4 + reg
  const int crow = (l >> 4) * 4, ccol = l & 15;
  #pragma unroll
  for (int m = 0; m < 4; ++m)
    #pragma unroll
    for (int n = 0; n < 4; ++n) {
      #pragma unroll
      for (int j = 0; j < 4; ++j)
        C[(size_t)(m0 + wm * 64 + m * 16 + crow + j) * N +
          (n0 + wn * 64 + n * 16 + ccol)] = acc[m][n][j];
    }
}

// ---------------- RoPE + RMSNorm, in place on q and k parts of qkv ----------
__global__ __launch_bounds__(256)
void rope_rms(float* __restrict__ qkv, const float* __restrict__ norm_w,
              const float* __restrict__ cosc, const float* __restrict__ sinc,
              const int* __restrict__ cu) {
  const int wid  = blockIdx.x * 4 + (threadIdx.x >> 6);
  const int lane = threadIdx.x & 63;
  const int t   = wid >> 5;
  const int rem = wid & 31;
  const int s   = rem >> 4;
  const int h   = rem & 15;
  const int b   = t >> 10;
  const int pos = t - cu[b];
  float* p = qkv + (size_t)t * QKVN + s * HID + h * HD;
  float x1 = p[lane], x2 = p[lane + 64];
  float c  = cosc[pos * 64 + lane];
  float sn = sinc[pos * 64 + lane];
  float y1 = x1 * c + x2 * sn;
  float y2 = x2 * c - x1 * sn;
  float ss = y1 * y1 + y2 * y2;
  #pragma unroll
  for (int o = 32; o > 0; o >>= 1) ss += __shfl_xor(ss, o, 64);
  float r = rsqrtf(ss * (1.0f / 128.0f) + 1e-6f);
  p[lane]      = y1 * r * norm_w[lane];
  p[lane + 64] = y2 * r * norm_w[lane + 64];
}

// ---------------- gate = sigmoid(x @ gate_w^T + gate_b), [N_TOK][NH] --------
__global__ __launch_bounds__(256)
void gate_kernel(const float* __restrict__ x, const float* __restrict__ gw,
                 const float* __restrict__ gb, float* __restrict__ gate) {
  __shared__ float xs[HID];
  const int t = blockIdx.x, tid = threadIdx.x;
  *(float4*)&xs[tid * 8]     = *(const float4*)&x[(size_t)t * HID + tid * 8];
  *(float4*)&xs[tid * 8 + 4] = *(const float4*)&x[(size_t)t * HID + tid * 8 + 4];
  __syncthreads();
  const int h = tid >> 4, i = tid & 15;
  const float* w  = gw + (size_t)h * HID + i * 128;
  const float* xx = xs + i * 128;
  float sum = 0.f;
  #pragma unroll
  for (int j = 0; j < 128; j += 4) {
    float4 wv = *(const float4*)(w + j);
    float4 xv = *(const float4*)(xx + j);
    sum += wv.x * xv.x + wv.y * xv.y + wv.z * xv.z + wv.w * xv.w;
  }
  sum += __shfl_xor(sum, 8, 64);
  sum += __shfl_xor(sum, 4, 64);
  sum += __shfl_xor(sum, 2, 64);
  sum += __shfl_xor(sum, 1, 64);
  if (i == 0) gate[t * NH + h] = 1.f / (1.f + __expf(-(sum + gb[h])));
}

// ---------------- causal flash attention, fp32, gate fused in epilogue ------
__global__ __launch_bounds__(256)
void attn_kernel(const float* __restrict__ qkv, const float* __restrict__ gate,
                 float* __restrict__ og) {
  constexpr int PADD = HD + 4;
  constexpr int PS   = 65;
  __shared__ float Qs[64][PADD];
  __shared__ float Ks[64][PADD];
  __shared__ float Vs[64][PADD];
  __shared__ float Ps[64][PS];
  const int bh = blockIdx.x, b = bh >> 4, h = bh & 15;
  const int qt = blockIdx.y;
  const int tid = threadIdx.x;
  const float scale = 0.08838834764831845f;
  const float* base = qkv + (size_t)b * SEQ * QKVN + h * HD;
  const float* qb = base;
  const float* kb = base + HID;
  const float* vb = base + 2 * HID;
  {
    const int r = tid >> 2, cg = (tid & 3) * 32;
    const float* src = qb + (size_t)(qt * 64 + r) * QKVN + cg;
    #pragma unroll
    for (int j = 0; j < 32; j += 4) {
      float4 v = *(const float4*)(src + j);
      v.x *= scale; v.y *= scale; v.z *= scale; v.w *= scale;
      *(float4*)&Qs[r][cg + j] = v;
    }
  }
  float O[32] = {};
  float m_run = -INFINITY, l_run = 0.f;
  const int orow = tid >> 2, oi = tid & 3;
  const int tr = tid >> 4, tc = tid & 15;
  for (int kt = 0; kt <= qt; ++kt) {
    __syncthreads();
    {
      const int r = tid >> 2, cg = (tid & 3) * 32;
      const float* ksrc = kb + (size_t)(kt * 64 + r) * QKVN + cg;
      const float* vsrc = vb + (size_t)(kt * 64 + r) * QKVN + cg;
      #pragma unroll
      for (int j = 0; j < 32; j += 4) {
        *(float4*)&Ks[r][cg + j] = *(const float4*)(ksrc + j);
        *(float4*)&Vs[r][cg + j] = *(const float4*)(vsrc + j);
      }
    }
    __syncthreads();
    float s[4][4] = {};
    #pragma unroll
    for (int k4 = 0; k4 < HD / 4; ++k4) {
      float4 q_[4], k_[4];
      #pragma unroll
      for (int i = 0; i < 4; ++i) q_[i] = *(const float4*)&Qs[tr * 4 + i][k4 * 4];
      #pragma unroll
      for (int j = 0; j < 4; ++j) k_[j] = *(const float4*)&Ks[tc + 16 * j][k4 * 4];
      #pragma unroll
      for (int i = 0; i < 4; ++i)
        #pragma unroll
        for (int j = 0; j < 4; ++j)
          s[i][j] += q_[i].x * k_[j].x + q_[i].y * k_[j].y +
                     q_[i].z * k_[j].z + q_[i].w * k_[j].w;
    }
    if (kt == qt) {
      #pragma unroll
      for (int i = 0; i < 4; ++i)
        #pragma unroll
        for (int j = 0; j < 4; ++j)
          if (tc + 16 * j > tr * 4 + i) s[i][j] = -INFINITY;
    }
    #pragma unroll
    for (int i = 0; i < 4; ++i)
      #pragma unroll
      for (int j = 0; j < 4; ++j)
        Ps[tr * 4 + i][tc + 16 * j] = s[i][j];
    __syncthreads();
    {
      const int r = orow, seg = oi * 16;
      float mx = -INFINITY;
      #pragma unroll
      for (int j = 0; j < 16; ++j) mx = fmaxf(mx, Ps[r][seg + j]);
      mx = fmaxf(mx, __shfl_xor(mx, 1, 64));
      mx = fmaxf(mx, __shfl_xor(mx, 2, 64));
      float mnew = fmaxf(m_run, mx);
      float corr = __expf(m_run - mnew);
      float ls = 0.f;
      #pragma unroll
      for (int j = 0; j < 16; ++j) {
        float pv = __expf(Ps[r][seg + j] - mnew);
        Ps[r][seg + j] = pv;
        ls += pv;
      }
      ls += __shfl_xor(ls, 1, 64);
      ls += __shfl_xor(ls, 2, 64);
      l_run = l_run * corr + ls;
      m_run = mnew;
      #pragma unroll
      for (int c = 0; c < 32; ++c) O[c] *= corr;
    }
    __syncthreads();
    #pragma unroll 4
    for (int j = 0; j < 64; ++j) {
      float pv = Ps[orow][j];
      #pragma unroll
      for (int c4 = 0; c4 < 8; ++c4) {
        float4 vv = *(const float4*)&Vs[j][c4 * 16 + oi * 4];
        O[c4 * 4 + 0] = fmaf(pv, vv.x, O[c4 * 4 + 0]);
        O[c4 * 4 + 1] = fmaf(pv, vv.y, O[c4 * 4 + 1]);
        O[c4 * 4 + 2] = fmaf(pv, vv.z, O[c4 * 4 + 2]);
        O[c4 * 4 + 3] = fmaf(pv, vv.w, O[c4 * 4 + 3]);
      }
    }
  }
  {
    const int t = b * SEQ + qt * 64 + orow;
    const float g = gate[t * NH + h];
    const float inv = g / l_run;
    float* dst = og + (size_t)t * HID + h * HD;
    #pragma unroll
    for (int c4 = 0; c4 < 8; ++c4) {
      float4 o4 = make_float4(O[c4 * 4 + 0] * inv, O[c4 * 4 + 1] * inv,
                              O[c4 * 4 + 2] * inv, O[c4 * 4 + 3] * inv);
      *(float4*)&dst[c4 * 16 + oi * 4] = o4;
    }
  }
}

extern "C" void kernel_launch(void* const* d_in, const int* in_sizes, int n_in,
                              void* d_out, int out_size, void* d_ws, size_t ws_size,
                              hipStream_t stream) {
  const float* x    = (const float*)d_in[0];
  const float* Wqkv = (const float*)d_in[1];
  const float* Wo   = (const float*)d_in[2];
  const float* gw   = (const float*)d_in[3];
  const float* gb   = (const float*)d_in[4];
  const float* nw   = (const float*)d_in[5];
  const float* cosc = (const float*)d_in[6];
  const float* sinc = (const float*)d_in[7];
  const int*   cu   = (const int*)d_in[8];
  float* out = (float*)d_out;

  float*  qkv  = (float*)d_ws;                        // [4096][6144] f32
  float*  attn = qkv + (size_t)N_TOK * QKVN;          // [4096][2048] f32
  float*  gate = attn + (size_t)N_TOK * HID;          // [4096][16]   f32
  ushort* Abuf = (ushort*)(gate + (size_t)N_TOK * NH);     // [4096][6144] bf16
  ushort* Bbuf = Abuf + (size_t)N_TOK * KSPLIT;            // [6144][6144] bf16

  // 1) QKV projection: split x and Wqkv, then bf16 MFMA GEMM (K'=6144)
  split_bf16<<<2048, 256, 0, stream>>>(x,    Abuf, N_TOK * HID / 4, 1);
  split_bf16<<<2048, 256, 0, stream>>>(Wqkv, Bbuf, QKVN * HID / 4, 0);
  gemm_bf16_nt<<<dim3(QKVN / 128, N_TOK / 128), 256, 0, stream>>>(
      Abuf, Bbuf, qkv, N_TOK, QKVN, KSPLIT);

  // 2) RoPE + RMSNorm (in place on q,k), gate, attention
  rope_rms<<<dim3(N_TOK * 2 * NH / 4), 256, 0, stream>>>(qkv, nw, cosc, sinc, cu);
  gate_kernel<<<dim3(N_TOK), 256, 0, stream>>>(x, gw, gb, gate);
  attn_kernel<<<dim3(NSEQ * NH, SEQ / 64), 256, 0, stream>>>(qkv, gate, attn);

  // 3) Output projection: split attn and Wo, bf16 MFMA GEMM
  split_bf16<<<2048, 256, 0, stream>>>(attn, Abuf, N_TOK * HID / 4, 1);
  split_bf16<<<2048, 256, 0, stream>>>(Wo,   Bbuf, HID * HID / 4, 0);
  gemm_bf16_nt<<<dim3(HID / 128, N_TOK / 128), 256, 0, stream>>>(
      Abuf, Bbuf, out, N_TOK, HID, KSPLIT);
}

// Round 3
// 976.390 us; speedup vs baseline: 2.7646x; 1.4741x over previous
//
#include <hip/hip_runtime.h>
#include <hip/hip_bf16.h>
#include <math.h>

#define N_TOK 4096
#define HID   2048
#define NH    16
#define HD    128
#define SEQ   1024
#define NSEQ  4
#define QKVN  (3*HID)   // 6144
#define KSPLIT (3*HID)  // split-K width: [hi|hi|lo] x [hi|lo|hi]

typedef __bf16 bf16x8 __attribute__((ext_vector_type(8)));
typedef float  f32x4  __attribute__((ext_vector_type(4)));
typedef unsigned short ushort8v __attribute__((ext_vector_type(8)));

#define MFMA16(a,b,c) __builtin_amdgcn_mfma_f32_16x16x32_bf16(a,b,c,0,0,0)

__device__ __forceinline__ ushort bf16_rn(float f) {
  unsigned u = __float_as_uint(f);
  return (ushort)((u + 0x7FFFu + ((u >> 16) & 1u)) >> 16);
}
__device__ __forceinline__ float bf16_tof(ushort h) {
  return __uint_as_float(((unsigned)h) << 16);
}
__device__ __forceinline__ void gload16(const void* g, void* l) {
  __builtin_amdgcn_global_load_lds(
      (const __attribute__((address_space(1))) void*)g,
      (__attribute__((address_space(3))) void*)l, 16, 0, 0);
}

// ---- split fp32 [R][2048] -> bf16 [R][6144] as [hi | X | Y] ----------------
__global__ __launch_bounds__(256)
void split_bf16(const float* __restrict__ src, ushort* __restrict__ dst,
                int total4, int amode) {
  for (int idx = blockIdx.x * 256 + threadIdx.x; idx < total4;
       idx += gridDim.x * 256) {
    const int r = idx >> 9, kq = idx & 511;
    float4 v = ((const float4*)src)[idx];
    float f[4] = {v.x, v.y, v.z, v.w};
    ushort h[4], lo[4];
    #pragma unroll
    for (int j = 0; j < 4; ++j) {
      h[j]  = bf16_rn(f[j]);
      lo[j] = bf16_rn(f[j] - bf16_tof(h[j]));
    }
    ushort4 hv = make_ushort4(h[0], h[1], h[2], h[3]);
    ushort4 lv = make_ushort4(lo[0], lo[1], lo[2], lo[3]);
    ushort* row = dst + (size_t)r * KSPLIT + kq * 4;
    *(ushort4*)(row)        = hv;
    *(ushort4*)(row + 2048) = amode ? hv : lv;
    *(ushort4*)(row + 4096) = amode ? lv : hv;
  }
}

// ---- bf16 MFMA GEMM (m97 structure) + T1 XCD swizzle ----------------------
__global__ __launch_bounds__(256)
void gemm_bf16_nt(const ushort* __restrict__ A, const ushort* __restrict__ B,
                  float* __restrict__ C, int M, int N, int K) {
  __shared__ ushort As[128 * 32];
  __shared__ ushort Bs[128 * 32];
  const int nx = gridDim.x;
  const int nwg = nx * gridDim.y;
  const int bid = blockIdx.y * nx + blockIdx.x;
  const int cpx = nwg >> 3;                    // nwg % 8 == 0 for our grids
  const int swz = (bid & 7) * cpx + (bid >> 3);
  const int bx = swz % nx, by = swz / nx;
  const int tid = threadIdx.x;
  const int w = tid >> 6, l = tid & 63;
  const int wm = w >> 1, wn = w & 1;
  const int m0 = by * 128, n0 = bx * 128;
  const int lr = l & 15;
  const int ko = (l >> 4) * 8;
  const int srow = l >> 2;
  const int scol = (l & 3) * 8;

  f32x4 acc[4][4];
  #pragma unroll
  for (int m = 0; m < 4; ++m)
    #pragma unroll
    for (int n = 0; n < 4; ++n)
      acc[m][n] = (f32x4){0.f, 0.f, 0.f, 0.f};

  for (int k0 = 0; k0 < K; k0 += 32) {
    #pragma unroll
    for (int i = 0; i < 2; ++i) {
      const int rbase = w * 32 + i * 16;
      const ushort* ga = A + (size_t)(m0 + rbase + srow) * K + k0 + scol;
      const ushort* gb = B + (size_t)(n0 + rbase + srow) * K + k0 + scol;
      gload16(ga, &As[rbase * 32]);
      gload16(gb, &Bs[rbase * 32]);
    }
    __syncthreads();
    bf16x8 av[4], bv[4];
    #pragma unroll
    for (int m = 0; m < 4; ++m)
      av[m] = *(const bf16x8*)&As[(wm * 64 + m * 16 + lr) * 32 + ko];
    #pragma unroll
    for (int n = 0; n < 4; ++n)
      bv[n] = *(const bf16x8*)&Bs[(wn * 64 + n * 16 + lr) * 32 + ko];
    #pragma unroll
    for (int m = 0; m < 4; ++m)
      #pragma unroll
      for (int n = 0; n < 4; ++n)
        acc[m][n] = MFMA16(av[m], bv[n], acc[m][n]);
    __syncthreads();
  }
  const int crow = (l >> 4) * 4, ccol = l & 15;
  #pragma unroll
  for (int m = 0; m < 4; ++m)
    #pragma unroll
    for (int n = 0; n < 4; ++n) {
      #pragma unroll
      for (int j = 0; j < 4; ++j)
        C[(size_t)(m0 + wm * 64 + m * 16 + crow + j) * N +
          (n0 + wn * 64 + n * 16 + ccol)] = acc[m][n][j];
    }
}

// ---- RoPE + RMSNorm -> swizzled split-bf16 Qsp/Ksp [token][h][hi128|lo128] -
// Q pre-scaled by 1/sqrt(128). Swizzle: byte_in_512B_row = (e*2) ^ ((t&7)<<4).
__global__ __launch_bounds__(256)
void rope_split(const float* __restrict__ qkv, const float* __restrict__ norm_w,
                const float* __restrict__ cosc, const float* __restrict__ sinc,
                const int* __restrict__ cu,
                ushort* __restrict__ Qsp, ushort* __restrict__ Ksp) {
  const int wid  = blockIdx.x * 4 + (threadIdx.x >> 6);
  const int lane = threadIdx.x & 63;
  const int t   = wid >> 5;
  const int rem = wid & 31;
  const int s   = rem >> 4;
  const int h   = rem & 15;
  const int pos = t - cu[t >> 10];
  const float* p = qkv + (size_t)t * QKVN + s * HID + h * HD;
  float x1 = p[lane], x2 = p[lane + 64];
  float c  = cosc[pos * 64 + lane];
  float sn = sinc[pos * 64 + lane];
  float y1 = x1 * c + x2 * sn;
  float y2 = x2 * c - x1 * sn;
  float ss = y1 * y1 + y2 * y2;
  #pragma unroll
  for (int o = 32; o > 0; o >>= 1) ss += __shfl_xor(ss, o, 64);
  float r = rsqrtf(ss * (1.0f / 128.0f) + 1e-6f);
  const float sc = s ? 1.0f : 0.08838834764831845f;
  float o1 = y1 * r * norm_w[lane] * sc;
  float o2 = y2 * r * norm_w[lane + 64] * sc;
  ushort h1 = bf16_rn(o1), l1 = bf16_rn(o1 - bf16_tof(h1));
  ushort h2 = bf16_rn(o2), l2 = bf16_rn(o2 - bf16_tof(h2));
  char* db = (char*)((s ? Ksp : Qsp) + ((size_t)t * NH + h) * 256);
  const int b0 = (lane * 2) ^ ((t & 7) << 4);
  *(ushort*)(db + b0)       = h1;   // hi[d]
  *(ushort*)(db + 128 + b0) = h2;   // hi[d+64]
  *(ushort*)(db + 256 + b0) = l1;   // lo[d]
  *(ushort*)(db + 384 + b0) = l2;   // lo[d+64]
}

// ---- V transpose+split: qkv v-part -> Vt[bh][256 drows][1024 keys] bf16 ----
// rows 0..127 = hi(d), 128..255 = lo(d). Swizzle: 16B chunk c -> c ^ (d&7)
// within each 128B k-tile segment.
__global__ __launch_bounds__(256)
void v_split_t(const float* __restrict__ qkv, ushort* __restrict__ Vt) {
  __shared__ float Vb[64][133];
  const int kt = blockIdx.x, bh = blockIdx.y;
  const int b = bh >> 4, h = bh & 15;
  const int tid = threadIdx.x;
  {
    const int k = tid >> 5, dm = (tid & 31) * 4;
    const float* src = qkv + (size_t)(b * SEQ + kt * 64) * QKVN + 2 * HID + h * HD;
    #pragma unroll
    for (int i = 0; i < 8; ++i) {
      float4 v = *(const float4*)(src + (size_t)(i * 8 + k) * QKVN + dm);
      Vb[i * 8 + k][dm]     = v.x;
      Vb[i * 8 + k][dm + 1] = v.y;
      Vb[i * 8 + k][dm + 2] = v.z;
      Vb[i * 8 + k][dm + 3] = v.w;
    }
  }
  __syncthreads();
  const int c  = tid & 7;
  const int d0 = tid >> 3;
  char* base = (char*)Vt + (size_t)bh * 256 * 2048;
  #pragma unroll
  for (int it = 0; it < 4; ++it) {
    const int d = d0 + it * 32;
    ushort8v vh, vl;
    #pragma unroll
    for (int j = 0; j < 8; ++j) {
      float f = Vb[c * 8 + j][d];
      ushort hh = bf16_rn(f);
      vh[j] = hh;
      vl[j] = bf16_rn(f - bf16_tof(hh));
    }
    const int cc = (c ^ (d & 7)) * 16;
    *(ushort8v*)(base + (size_t)d * 2048 + kt * 128 + cc)        = vh;
    *(ushort8v*)(base + (size_t)(128 + d) * 2048 + kt * 128 + cc) = vl;
  }
}

// ---- gate = sigmoid(x @ gate_w^T + gate_b) ---------------------------------
__global__ __launch_bounds__(256)
void gate_kernel(const float* __restrict__ x, const float* __restrict__ gw,
                 const float* __restrict__ gb, float* __restrict__ gate) {
  __shared__ float xs[HID];
  const int t = blockIdx.x, tid = threadIdx.x;
  *(float4*)&xs[tid * 8]     = *(const float4*)&x[(size_t)t * HID + tid * 8];
  *(float4*)&xs[tid * 8 + 4] = *(const float4*)&x[(size_t)t * HID + tid * 8 + 4];
  __syncthreads();
  const int h = tid >> 4, i = tid & 15;
  const float* w  = gw + (size_t)h * HID + i * 128;
  const float* xx = xs + i * 128;
  float sum = 0.f;
  #pragma unroll
  for (int j = 0; j < 128; j += 4) {
    float4 wv = *(const float4*)(w + j);
    float4 xv = *(const float4*)(xx + j);
    sum += wv.x * xv.x + wv.y * xv.y + wv.z * xv.z + wv.w * xv.w;
  }
  sum += __shfl_xor(sum, 8, 64);
  sum += __shfl_xor(sum, 4, 64);
  sum += __shfl_xor(sum, 2, 64);
  sum += __shfl_xor(sum, 1, 64);
  if (i == 0) gate[t * NH + h] = 1.f / (1.f + __expf(-(sum + gb[h])));
}

// ---- MFMA flash attention: 3-term split QK^T and PV ------------------------
__global__ __launch_bounds__(256, 1)
void attn_mfma(const ushort* __restrict__ Qsp, const ushort* __restrict__ Ksp,
               const ushort* __restrict__ Vtg, const float* __restrict__ gate,
               float* __restrict__ og) {
  __shared__ ushort Qs[64 * 256];    // 32 KB, [row][512B], swizzled
  __shared__ ushort Ks[64 * 256];    // 32 KB
  __shared__ ushort Vs[256 * 64];    // 32 KB, [drow][128B], swizzled
  __shared__ float  SP[64 * 66];     // 16.9 KB: S (f32 stride 66) / P (256B rows)
  __shared__ float  cf[64];
  const int bh = blockIdx.x, b = bh >> 4, h = bh & 15;
  const int qt = (int)gridDim.y - 1 - (int)blockIdx.y;  // heavy tiles first
  const int tid = threadIdx.x;
  const int w = tid >> 6, l = tid & 63;
  const int wm = w >> 1, wn = w & 1;
  const int fr = l & 15;
  const int fk = (l >> 4) * 16;          // k-group byte offset
  const int swr = (fr & 7) << 4;
  const int crow = (l >> 4) * 4, ccol = l & 15;
  const int sr = tid >> 2, so = tid & 3;

  // stage Q once (drains at first barrier)
  {
    const char* qg = (const char*)Qsp + ((size_t)(b * SEQ + qt * 64) * 16 + h) * 512
                     + (size_t)w * 131072 + (size_t)(l >> 5) * 8192 + (l & 31) * 16;
    char* qd = (char*)Qs + w * 8192;
    #pragma unroll
    for (int i = 0; i < 8; ++i) gload16(qg + i * 16384, qd + i * 1024);
  }
  const char* kg = (const char*)Ksp + ((size_t)(b * SEQ) * 16 + h) * 512
                   + (size_t)w * 131072 + (size_t)(l >> 5) * 8192 + (l & 31) * 16;
  const char* vg = (const char*)Vtg + ((size_t)bh * 256 + w * 64 + (l >> 3)) * 2048
                   + (l & 7) * 16;
  char* kd = (char*)Ks + w * 8192;
  char* vd = (char*)Vs + w * 8192;

  f32x4 acc_o[2][4];
  #pragma unroll
  for (int mi = 0; mi < 2; ++mi)
    #pragma unroll
    for (int ni = 0; ni < 4; ++ni)
      acc_o[mi][ni] = (f32x4){0.f, 0.f, 0.f, 0.f};
  float m_run = -INFINITY, l_run = 0.f;

  for (int kt = 0; kt <= qt; ++kt) {
    #pragma unroll
    for (int i = 0; i < 8; ++i) gload16(kg + i * 16384, kd + i * 1024);
    #pragma unroll
    for (int i = 0; i < 8; ++i) gload16(vg + i * 16384, vd + i * 1024);
    kg += 524288;  // next 64 tokens
    vg += 128;     // next 64 keys
    __syncthreads();   // B1: stage complete

    // ---- QK^T, 3-term split (Qhi*Khi + Qhi*Klo + Qlo*Khi) ----
    f32x4 acc_s[2][2];
    #pragma unroll
    for (int mi = 0; mi < 2; ++mi)
      #pragma unroll
      for (int ni = 0; ni < 2; ++ni)
        acc_s[mi][ni] = (f32x4){0.f, 0.f, 0.f, 0.f};
    #pragma unroll
    for (int term = 0; term < 3; ++term) {
      const int qo = (term == 2) ? 256 : 0;
      const int ko2 = (term == 1) ? 256 : 0;
      #pragma unroll
      for (int ks = 0; ks < 4; ++ks) {
        const int ia = (qo + ks * 64 + fk) ^ swr;
        const int ib = (ko2 + ks * 64 + fk) ^ swr;
        bf16x8 a0 = *(const bf16x8*)((const char*)Qs + (wm * 32 + fr) * 512 + ia);
        bf16x8 a1 = *(const bf16x8*)((const char*)Qs + (wm * 32 + 16 + fr) * 512 + ia);
        bf16x8 b0 = *(const bf16x8*)((const char*)Ks + (wn * 32 + fr) * 512 + ib);
        bf16x8 b1 = *(const bf16x8*)((const char*)Ks + (wn * 32 + 16 + fr) * 512 + ib);
        acc_s[0][0] = MFMA16(a0, b0, acc_s[0][0]);
        acc_s[0][1] = MFMA16(a0, b1, acc_s[0][1]);
        acc_s[1][0] = MFMA16(a1, b0, acc_s[1][0]);
        acc_s[1][1] = MFMA16(a1, b1, acc_s[1][1]);
      }
    }
    #pragma unroll
    for (int mi = 0; mi < 2; ++mi)
      #pragma unroll
      for (int ni = 0; ni < 2; ++ni)
        #pragma unroll
        for (int j = 0; j < 4; ++j)
          SP[(wm * 32 + mi * 16 + crow + j) * 66 + wn * 32 + ni * 16 + ccol] =
              acc_s[mi][ni][j];
    __syncthreads();   // B2: S complete

    // ---- online softmax (4 threads per row) ----
    float s[16];
    #pragma unroll
    for (int j = 0; j < 16; ++j) s[j] = SP[sr * 66 + so * 16 + j];
    __syncthreads();   // B3: S consumed; SP region becomes P

    {
      if (kt == qt) {
        #pragma unroll
        for (int j = 0; j < 16; ++j)
          if (so * 16 + j > sr) s[j] = -INFINITY;
      }
      float mx = -INFINITY;
      #pragma unroll
      for (int j = 0; j < 16; ++j) mx = fmaxf(mx, s[j]);
      mx = fmaxf(mx, __shfl_xor(mx, 1, 64));
      mx = fmaxf(mx, __shfl_xor(mx, 2, 64));
      float mnew = fmaxf(m_run, mx);
      float corr = __expf(m_run - mnew);
      float p[16];
      float ls = 0.f;
      #pragma unroll
      for (int j = 0; j < 16; ++j) { p[j] = __expf(s[j] - mnew); ls += p[j]; }
      ls += __shfl_xor(ls, 1, 64);
      ls += __shfl_xor(ls, 2, 64);
      l_run = l_run * corr + ls;
      m_run = mnew;
      char* prow = (char*)SP + sr * 256;
      const int swp = (sr & 7) << 4;
      #pragma unroll
      for (int half = 0; half < 2; ++half) {
        ushort8v vh, vl;
        #pragma unroll
        for (int j = 0; j < 8; ++j) {
          float pv = p[half * 8 + j];
          ushort hh = bf16_rn(pv);
          vh[j] = hh;
          vl[j] = bf16_rn(pv - bf16_tof(hh));
        }
        const int cb = (so * 32 + half * 16) ^ swp;
        *(ushort8v*)(prow + cb)       = vh;
        *(ushort8v*)(prow + 128 + cb) = vl;
      }
      if (so == 0) cf[sr] = corr;
    }
    __syncthreads();   // B4: P + corr ready

    // ---- rescale O, then PV: Phi*Vhi + Phi*Vlo + Plo*Vhi ----
    {
      float cl[8];
      #pragma unroll
      for (int mi = 0; mi < 2; ++mi)
        #pragma unroll
        for (int j = 0; j < 4; ++j)
          cl[mi * 4 + j] = cf[wm * 32 + mi * 16 + crow + j];
      #pragma unroll
      for (int mi = 0; mi < 2; ++mi)
        #pragma unroll
        for (int ni = 0; ni < 4; ++ni)
          #pragma unroll
          for (int j = 0; j < 4; ++j)
            acc_o[mi][ni][j] *= cl[mi * 4 + j];
      #pragma unroll
      for (int term = 0; term < 3; ++term) {
        const int po = (term == 2) ? 128 : 0;   // Plo byte offset
        const int vo = (term == 1) ? 128 : 0;   // Vlo row offset
        #pragma unroll
        for (int ks = 0; ks < 2; ++ks) {
          const int ip = (ks * 64 + fk) ^ swr;
          bf16x8 pa0 = *(const bf16x8*)((const char*)SP + (wm * 32 + fr) * 256 + po + ip);
          bf16x8 pa1 = *(const bf16x8*)((const char*)SP + (wm * 32 + 16 + fr) * 256 + po + ip);
          #pragma unroll
          for (int ni = 0; ni < 4; ++ni) {
            const int dr = vo + wn * 64 + ni * 16 + fr;   // dr&7 == fr&7
            bf16x8 vv = *(const bf16x8*)((const char*)Vs + dr * 128 + ((ks * 64 + fk) ^ swr));
            acc_o[0][ni] = MFMA16(pa0, vv, acc_o[0][ni]);
            acc_o[1][ni] = MFMA16(pa1, vv, acc_o[1][ni]);
          }
        }
      }
    }
    __syncthreads();   // B5: Ks/Vs/SP free for next iteration
  }

  // ---- epilogue: rowfac = gate / l, apply in C-layout, store ----
  if (so == 0) {
    const int t = b * SEQ + qt * 64 + sr;
    cf[sr] = gate[t * NH + h] / l_run;
  }
  __syncthreads();
  {
    float rf[8];
    #pragma unroll
    for (int mi = 0; mi < 2; ++mi)
      #pragma unroll
      for (int j = 0; j < 4; ++j)
        rf[mi * 4 + j] = cf[wm * 32 + mi * 16 + crow + j];
    #pragma unroll
    for (int mi = 0; mi < 2; ++mi)
      #pragma unroll
      for (int ni = 0; ni < 4; ++ni)
        #pragma unroll
        for (int j = 0; j < 4; ++j)
          og[(size_t)(b * SEQ + qt * 64 + wm * 32 + mi * 16 + crow + j) * HID
             + h * HD + wn * 64 + ni * 16 + ccol] = acc_o[mi][ni][j] * rf[mi * 4 + j];
  }
}

extern "C" void kernel_launch(void* const* d_in, const int* in_sizes, int n_in,
                              void* d_out, int out_size, void* d_ws, size_t ws_size,
                              hipStream_t stream) {
  const float* x    = (const float*)d_in[0];
  const float* Wqkv = (const float*)d_in[1];
  const float* Wo   = (const float*)d_in[2];
  const float* gw   = (const float*)d_in[3];
  const float* gb   = (const float*)d_in[4];
  const float* nw   = (const float*)d_in[5];
  const float* cosc = (const float*)d_in[6];
  const float* sinc = (const float*)d_in[7];
  const int*   cu   = (const int*)d_in[8];
  float* out = (float*)d_out;

  float*  qkv  = (float*)d_ws;                         // [4096][6144] f32
  float*  attn = qkv + (size_t)N_TOK * QKVN;           // [4096][2048] f32
  float*  gate = attn + (size_t)N_TOK * HID;           // [4096][16]   f32
  ushort* Abuf = (ushort*)(gate + (size_t)N_TOK * NH); // 50.3 MB bf16
  ushort* Bbuf = Abuf + (size_t)N_TOK * KSPLIT;        // 75.5 MB bf16
  // attention split buffers alias A/B (free between QKV-GEMM and out-proj)
  ushort* Qsp = Abuf;                                  // [4096][16][256]
  ushort* Ksp = Bbuf;                                  // [4096][16][256]
  ushort* Vt  = Bbuf + (size_t)N_TOK * NH * 256;       // [64][256][1024]

  // 1) QKV projection (split-bf16 MFMA, K'=6144)
  split_bf16<<<2048, 256, 0, stream>>>(x,    Abuf, N_TOK * HID / 4, 1);
  split_bf16<<<2048, 256, 0, stream>>>(Wqkv, Bbuf, QKVN * HID / 4, 0);
  gemm_bf16_nt<<<dim3(QKVN / 128, N_TOK / 128), 256, 0, stream>>>(
      Abuf, Bbuf, qkv, N_TOK, QKVN, KSPLIT);

  // 2) producers for MFMA attention
  rope_split<<<dim3(N_TOK * 2 * NH / 4), 256, 0, stream>>>(qkv, nw, cosc, sinc,
                                                           cu, Qsp, Ksp);
  v_split_t<<<dim3(16, 64), 256, 0, stream>>>(qkv, Vt);
  gate_kernel<<<dim3(N_TOK), 256, 0, stream>>>(x, gw, gb, gate);

  // 3) MFMA flash attention (gate fused)
  attn_mfma<<<dim3(NSEQ * NH, SEQ / 64), 256, 0, stream>>>(Qsp, Ksp, Vt, gate, attn);

  // 4) output projection
  split_bf16<<<2048, 256, 0, stream>>>(attn, Abuf, N_TOK * HID / 4, 1);
  split_bf16<<<2048, 256, 0, stream>>>(Wo,   Bbuf, HID * HID / 4, 0);
  gemm_bf16_nt<<<dim3(HID / 128, N_TOK / 128), 256, 0, stream>>>(
      Abuf, Bbuf, out, N_TOK, HID, KSPLIT);
}

// Round 4
// 875.730 us; speedup vs baseline: 3.0824x; 1.1149x over previous
//
#include <hip/hip_runtime.h>
#include <hip/hip_bf16.h>
#include <math.h>

#define N_TOK 4096
#define HID   2048
#define NH    16
#define HD    128
#define SEQ   1024
#define NSEQ  4
#define QKVN  (3*HID)   // 6144
#define KSPLIT (3*HID)  // split-K width: [hi|hi|lo] x [hi|lo|hi]

typedef __bf16 bf16x8 __attribute__((ext_vector_type(8)));
typedef float  f32x4  __attribute__((ext_vector_type(4)));
typedef unsigned short ushort8v __attribute__((ext_vector_type(8)));

#define MFMA16(a,b,c) __builtin_amdgcn_mfma_f32_16x16x32_bf16(a,b,c,0,0,0)

__device__ __forceinline__ ushort bf16_rn(float f) {
  unsigned u = __float_as_uint(f);
  return (ushort)((u + 0x7FFFu + ((u >> 16) & 1u)) >> 16);
}
__device__ __forceinline__ float bf16_tof(ushort h) {
  return __uint_as_float(((unsigned)h) << 16);
}
__device__ __forceinline__ void gload16(const void* g, void* l) {
  __builtin_amdgcn_global_load_lds(
      (const __attribute__((address_space(1))) void*)g,
      (__attribute__((address_space(3))) void*)l, 16, 0, 0);
}

// compiler+scheduler fence around raw barriers (rule #18/m152)
#define CFENCE asm volatile("" ::: "memory")
#define BARR do { __builtin_amdgcn_sched_barrier(0); CFENCE; \
                  __builtin_amdgcn_s_barrier(); CFENCE; \
                  __builtin_amdgcn_sched_barrier(0); } while (0)
#define VMCNT4 do { __builtin_amdgcn_sched_barrier(0); \
                    asm volatile("s_waitcnt vmcnt(4)" ::: "memory"); } while (0)

// ---- split fp32 [R][2048] -> bf16 [R][6144] as [hi | X | Y] ----------------
__global__ __launch_bounds__(256)
void split_bf16(const float* __restrict__ src, ushort* __restrict__ dst,
                int total4, int amode) {
  for (int idx = blockIdx.x * 256 + threadIdx.x; idx < total4;
       idx += gridDim.x * 256) {
    const int r = idx >> 9, kq = idx & 511;
    float4 v = ((const float4*)src)[idx];
    float f[4] = {v.x, v.y, v.z, v.w};
    ushort h[4], lo[4];
    #pragma unroll
    for (int j = 0; j < 4; ++j) {
      h[j]  = bf16_rn(f[j]);
      lo[j] = bf16_rn(f[j] - bf16_tof(h[j]));
    }
    ushort4 hv = make_ushort4(h[0], h[1], h[2], h[3]);
    ushort4 lv = make_ushort4(lo[0], lo[1], lo[2], lo[3]);
    ushort* row = dst + (size_t)r * KSPLIT + kq * 4;
    *(ushort4*)(row)        = hv;
    *(ushort4*)(row + 2048) = amode ? hv : lv;
    *(ushort4*)(row + 4096) = amode ? lv : hv;
  }
}

// ---- 256x256 deep-pipelined bf16 MFMA GEMM (T1+T2+T3+T4+T5) ---------------
// BK=64, 512 threads = 8 waves (2M x 4N), per-wave C = 128x64.
// LDS 128 KB dynamic: 2 buf x [A: 2 ksub x 256 x 32, B same] (ushort).
// Counted vmcnt(4) twice per K-tile; ds_read chunk-XOR swizzle both-sides.
__global__ __launch_bounds__(512, 2)
void gemm256(const ushort* __restrict__ A, const ushort* __restrict__ B,
             float* __restrict__ C, int M, int N, int K) {
  extern __shared__ ushort lds[];
  const int nx = gridDim.x;
  const int nwg = nx * gridDim.y;
  const int bid = blockIdx.y * nx + blockIdx.x;
  const int cpx = nwg >> 3;                    // grids are %8==0
  const int swz = (bid & 7) * cpx + (bid >> 3);
  const int bx = swz % nx, by = swz / nx;
  const int m0 = by * 256, n0 = bx * 256;
  const int tid = threadIdx.x;
  const int w = tid >> 6, l = tid & 63;
  const int wm = w >> 2, wn = w & 3;
  const int fr = l & 15, kc = l >> 4;
  const int cx = (kc ^ ((fr >> 1) & 3)) * 8;       // swizzled 16B chunk (us)
  const int aoff = (wm * 128 + fr) * 32 + cx;      // A frag base (us)
  const int boff = 16384 + (wn * 64 + fr) * 32 + cx; // B frag base (us)
  const int tr0 = tid >> 2;                        // staging row (i=0)
  const int q0c = tid & 3;                         // staging chunk slot
  const int wub = (tid & 448) * 8;                 // wave-uniform LDS chunk base
  const int NTILE = K >> 6;

  auto stage = [&](int bufus, int kt, int s) {
    const int koe = kt * 64 + s * 32;
    #pragma unroll
    for (int i = 0; i < 2; ++i) {
      const int tr = i * 128 + tr0;
      const int gq = (q0c ^ ((tr >> 1) & 3)) * 8;
      gload16(A + (size_t)(m0 + tr) * K + koe + gq,
              &lds[bufus + s * 8192 + i * 8192 / 2 * 0 + (i * 512) * 8 + wub]);
    }
    #pragma unroll
    for (int i = 0; i < 2; ++i) {
      const int tr = i * 128 + tr0;
      const int gq = (q0c ^ ((tr >> 1) & 3)) * 8;
      gload16(B + (size_t)(n0 + tr) * K + koe + gq,
              &lds[bufus + 16384 + s * 8192 + (i * 512) * 8 + wub]);
    }
  };
  auto lda4 = [&](bf16x8* dst, int cb, int s, int mbase) {
    #pragma unroll
    for (int m = 0; m < 4; ++m)
      dst[m] = *(const bf16x8*)&lds[cb + s * 8192 + aoff + (mbase + m) * 512];
  };
  auto ldb4 = [&](bf16x8* dst, int cb, int s) {
    #pragma unroll
    for (int n = 0; n < 4; ++n)
      dst[n] = *(const bf16x8*)&lds[cb + s * 8192 + boff + n * 512];
  };

  f32x4 acc[8][4];
  #pragma unroll
  for (int m = 0; m < 8; ++m)
    #pragma unroll
    for (int n = 0; n < 4; ++n)
      acc[m][n] = (f32x4){0.f, 0.f, 0.f, 0.f};

  auto mm = [&](bf16x8* av_, bf16x8* bv_, int mbase) {
    __builtin_amdgcn_s_setprio(1);
    #pragma unroll
    for (int m = 0; m < 4; ++m)
      #pragma unroll
      for (int n = 0; n < 4; ++n)
        acc[mbase + m][n] = MFMA16(av_[m], bv_[n], acc[mbase + m][n]);
    __builtin_amdgcn_s_setprio(0);
  };

  // prologue: tile 0, both ksub pairs; verify k0 landed (k1 stays in flight)
  stage(0, 0, 0);
  stage(0, 0, 1);
  VMCNT4;
  BARR;

  for (int T = 0; T < NTILE; ++T) {
    const int cb = (T & 1) << 15;        // current buffer (us offset)
    const int nb = 32768 - cb;           // next buffer
    const bool st = (T + 1) < NTILE;
    bf16x8 a0[4], b0[4], a1[4];
    // q0: ksub0, C rows m0-3
    lda4(a0, cb, 0, 0);
    ldb4(b0, cb, 0);
    if (st) stage(nb, T + 1, 0);
    BARR;
    mm(a0, b0, 0);
    BARR;
    // q1: ksub0, C rows m4-7 (reuse b0)
    lda4(a1, cb, 0, 4);
    VMCNT4;                              // lands cur.k1 (newest 4 = next.k0)
    BARR;
    mm(a1, b0, 4);
    BARR;
    // q2: ksub1, rows m0-3
    lda4(a0, cb, 1, 0);
    ldb4(b0, cb, 1);
    if (st) stage(nb, T + 1, 1);
    BARR;
    mm(a0, b0, 0);
    BARR;
    // q3: ksub1, rows m4-7
    lda4(a1, cb, 1, 4);
    VMCNT4;                              // lands next.k0 (newest 4 = next.k1)
    BARR;
    mm(a1, b0, 4);
    BARR;
  }

  const int crow = (l >> 4) * 4, ccol = l & 15;
  #pragma unroll
  for (int m = 0; m < 8; ++m)
    #pragma unroll
    for (int n = 0; n < 4; ++n) {
      #pragma unroll
      for (int j = 0; j < 4; ++j)
        C[(size_t)(m0 + wm * 128 + m * 16 + crow + j) * N +
          (n0 + wn * 64 + n * 16 + ccol)] = acc[m][n][j];
    }
}

// ---- bf16 MFMA GEMM (m97 structure, known-good) — used for out-proj -------
__global__ __launch_bounds__(256)
void gemm_bf16_nt(const ushort* __restrict__ A, const ushort* __restrict__ B,
                  float* __restrict__ C, int M, int N, int K) {
  __shared__ ushort As[128 * 32];
  __shared__ ushort Bs[128 * 32];
  const int nx = gridDim.x;
  const int nwg = nx * gridDim.y;
  const int bid = blockIdx.y * nx + blockIdx.x;
  const int cpx = nwg >> 3;
  const int swz = (bid & 7) * cpx + (bid >> 3);
  const int bx = swz % nx, by = swz / nx;
  const int tid = threadIdx.x;
  const int w = tid >> 6, l = tid & 63;
  const int wm = w >> 1, wn = w & 1;
  const int m0 = by * 128, n0 = bx * 128;
  const int lr = l & 15;
  const int ko = (l >> 4) * 8;
  const int srow = l >> 2;
  const int scol = (l & 3) * 8;

  f32x4 acc[4][4];
  #pragma unroll
  for (int m = 0; m < 4; ++m)
    #pragma unroll
    for (int n = 0; n < 4; ++n)
      acc[m][n] = (f32x4){0.f, 0.f, 0.f, 0.f};

  for (int k0 = 0; k0 < K; k0 += 32) {
    #pragma unroll
    for (int i = 0; i < 2; ++i) {
      const int rbase = w * 32 + i * 16;
      const ushort* ga = A + (size_t)(m0 + rbase + srow) * K + k0 + scol;
      const ushort* gb = B + (size_t)(n0 + rbase + srow) * K + k0 + scol;
      gload16(ga, &As[rbase * 32]);
      gload16(gb, &Bs[rbase * 32]);
    }
    __syncthreads();
    bf16x8 av[4], bv[4];
    #pragma unroll
    for (int m = 0; m < 4; ++m)
      av[m] = *(const bf16x8*)&As[(wm * 64 + m * 16 + lr) * 32 + ko];
    #pragma unroll
    for (int n = 0; n < 4; ++n)
      bv[n] = *(const bf16x8*)&Bs[(wn * 64 + n * 16 + lr) * 32 + ko];
    #pragma unroll
    for (int m = 0; m < 4; ++m)
      #pragma unroll
      for (int n = 0; n < 4; ++n)
        acc[m][n] = MFMA16(av[m], bv[n], acc[m][n]);
    __syncthreads();
  }
  const int crow = (l >> 4) * 4, ccol = l & 15;
  #pragma unroll
  for (int m = 0; m < 4; ++m)
    #pragma unroll
    for (int n = 0; n < 4; ++n) {
      #pragma unroll
      for (int j = 0; j < 4; ++j)
        C[(size_t)(m0 + wm * 64 + m * 16 + crow + j) * N +
          (n0 + wn * 64 + n * 16 + ccol)] = acc[m][n][j];
    }
}

// ---- RoPE + RMSNorm -> swizzled split-bf16 Qsp/Ksp -------------------------
__global__ __launch_bounds__(256)
void rope_split(const float* __restrict__ qkv, const float* __restrict__ norm_w,
                const float* __restrict__ cosc, const float* __restrict__ sinc,
                const int* __restrict__ cu,
                ushort* __restrict__ Qsp, ushort* __restrict__ Ksp) {
  const int wid  = blockIdx.x * 4 + (threadIdx.x >> 6);
  const int lane = threadIdx.x & 63;
  const int t   = wid >> 5;
  const int rem = wid & 31;
  const int s   = rem >> 4;
  const int h   = rem & 15;
  const int pos = t - cu[t >> 10];
  const float* p = qkv + (size_t)t * QKVN + s * HID + h * HD;
  float x1 = p[lane], x2 = p[lane + 64];
  float c  = cosc[pos * 64 + lane];
  float sn = sinc[pos * 64 + lane];
  float y1 = x1 * c + x2 * sn;
  float y2 = x2 * c - x1 * sn;
  float ss = y1 * y1 + y2 * y2;
  #pragma unroll
  for (int o = 32; o > 0; o >>= 1) ss += __shfl_xor(ss, o, 64);
  float r = rsqrtf(ss * (1.0f / 128.0f) + 1e-6f);
  const float sc = s ? 1.0f : 0.08838834764831845f;
  float o1 = y1 * r * norm_w[lane] * sc;
  float o2 = y2 * r * norm_w[lane + 64] * sc;
  ushort h1 = bf16_rn(o1), l1 = bf16_rn(o1 - bf16_tof(h1));
  ushort h2 = bf16_rn(o2), l2 = bf16_rn(o2 - bf16_tof(h2));
  char* db = (char*)((s ? Ksp : Qsp) + ((size_t)t * NH + h) * 256);
  const int b0 = (lane * 2) ^ ((t & 7) << 4);
  *(ushort*)(db + b0)       = h1;
  *(ushort*)(db + 128 + b0) = h2;
  *(ushort*)(db + 256 + b0) = l1;
  *(ushort*)(db + 384 + b0) = l2;
}

// ---- V transpose+split -----------------------------------------------------
__global__ __launch_bounds__(256)
void v_split_t(const float* __restrict__ qkv, ushort* __restrict__ Vt) {
  __shared__ float Vb[64][133];
  const int kt = blockIdx.x, bh = blockIdx.y;
  const int b = bh >> 4, h = bh & 15;
  const int tid = threadIdx.x;
  {
    const int k = tid >> 5, dm = (tid & 31) * 4;
    const float* src = qkv + (size_t)(b * SEQ + kt * 64) * QKVN + 2 * HID + h * HD;
    #pragma unroll
    for (int i = 0; i < 8; ++i) {
      float4 v = *(const float4*)(src + (size_t)(i * 8 + k) * QKVN + dm);
      Vb[i * 8 + k][dm]     = v.x;
      Vb[i * 8 + k][dm + 1] = v.y;
      Vb[i * 8 + k][dm + 2] = v.z;
      Vb[i * 8 + k][dm + 3] = v.w;
    }
  }
  __syncthreads();
  const int c  = tid & 7;
  const int d0 = tid >> 3;
  char* base = (char*)Vt + (size_t)bh * 256 * 2048;
  #pragma unroll
  for (int it = 0; it < 4; ++it) {
    const int d = d0 + it * 32;
    ushort8v vh, vl;
    #pragma unroll
    for (int j = 0; j < 8; ++j) {
      float f = Vb[c * 8 + j][d];
      ushort hh = bf16_rn(f);
      vh[j] = hh;
      vl[j] = bf16_rn(f - bf16_tof(hh));
    }
    const int cc = (c ^ (d & 7)) * 16;
    *(ushort8v*)(base + (size_t)d * 2048 + kt * 128 + cc)        = vh;
    *(ushort8v*)(base + (size_t)(128 + d) * 2048 + kt * 128 + cc) = vl;
  }
}

// ---- gate = sigmoid(x @ gate_w^T + gate_b) ---------------------------------
__global__ __launch_bounds__(256)
void gate_kernel(const float* __restrict__ x, const float* __restrict__ gw,
                 const float* __restrict__ gb, float* __restrict__ gate) {
  __shared__ float xs[HID];
  const int t = blockIdx.x, tid = threadIdx.x;
  *(float4*)&xs[tid * 8]     = *(const float4*)&x[(size_t)t * HID + tid * 8];
  *(float4*)&xs[tid * 8 + 4] = *(const float4*)&x[(size_t)t * HID + tid * 8 + 4];
  __syncthreads();
  const int h = tid >> 4, i = tid & 15;
  const float* w  = gw + (size_t)h * HID + i * 128;
  const float* xx = xs + i * 128;
  float sum = 0.f;
  #pragma unroll
  for (int j = 0; j < 128; j += 4) {
    float4 wv = *(const float4*)(w + j);
    float4 xv = *(const float4*)(xx + j);
    sum += wv.x * xv.x + wv.y * xv.y + wv.z * xv.z + wv.w * xv.w;
  }
  sum += __shfl_xor(sum, 8, 64);
  sum += __shfl_xor(sum, 4, 64);
  sum += __shfl_xor(sum, 2, 64);
  sum += __shfl_xor(sum, 1, 64);
  if (i == 0) gate[t * NH + h] = 1.f / (1.f + __expf(-(sum + gb[h])));
}

// ---- MFMA flash attention: 3-term split QK^T and PV ------------------------
__global__ __launch_bounds__(256, 1)
void attn_mfma(const ushort* __restrict__ Qsp, const ushort* __restrict__ Ksp,
               const ushort* __restrict__ Vtg, const float* __restrict__ gate,
               float* __restrict__ og) {
  __shared__ ushort Qs[64 * 256];
  __shared__ ushort Ks[64 * 256];
  __shared__ ushort Vs[256 * 64];
  __shared__ float  SP[64 * 66];
  __shared__ float  cf[64];
  const int bh = blockIdx.x, b = bh >> 4, h = bh & 15;
  const int qt = (int)gridDim.y - 1 - (int)blockIdx.y;
  const int tid = threadIdx.x;
  const int w = tid >> 6, l = tid & 63;
  const int wm = w >> 1, wn = w & 1;
  const int fr = l & 15;
  const int fk = (l >> 4) * 16;
  const int swr = (fr & 7) << 4;
  const int crow = (l >> 4) * 4, ccol = l & 15;
  const int sr = tid >> 2, so = tid & 3;

  {
    const char* qg = (const char*)Qsp + ((size_t)(b * SEQ + qt * 64) * 16 + h) * 512
                     + (size_t)w * 131072 + (size_t)(l >> 5) * 8192 + (l & 31) * 16;
    char* qd = (char*)Qs + w * 8192;
    #pragma unroll
    for (int i = 0; i < 8; ++i) gload16(qg + i * 16384, qd + i * 1024);
  }
  const char* kg = (const char*)Ksp + ((size_t)(b * SEQ) * 16 + h) * 512
                   + (size_t)w * 131072 + (size_t)(l >> 5) * 8192 + (l & 31) * 16;
  const char* vg = (const char*)Vtg + ((size_t)bh * 256 + w * 64 + (l >> 3)) * 2048
                   + (l & 7) * 16;
  char* kd = (char*)Ks + w * 8192;
  char* vd = (char*)Vs + w * 8192;

  f32x4 acc_o[2][4];
  #pragma unroll
  for (int mi = 0; mi < 2; ++mi)
    #pragma unroll
    for (int ni = 0; ni < 4; ++ni)
      acc_o[mi][ni] = (f32x4){0.f, 0.f, 0.f, 0.f};
  float m_run = -INFINITY, l_run = 0.f;

  for (int kt = 0; kt <= qt; ++kt) {
    #pragma unroll
    for (int i = 0; i < 8; ++i) gload16(kg + i * 16384, kd + i * 1024);
    #pragma unroll
    for (int i = 0; i < 8; ++i) gload16(vg + i * 16384, vd + i * 1024);
    kg += 524288;
    vg += 128;
    __syncthreads();

    f32x4 acc_s[2][2];
    #pragma unroll
    for (int mi = 0; mi < 2; ++mi)
      #pragma unroll
      for (int ni = 0; ni < 2; ++ni)
        acc_s[mi][ni] = (f32x4){0.f, 0.f, 0.f, 0.f};
    #pragma unroll
    for (int term = 0; term < 3; ++term) {
      const int qo = (term == 2) ? 256 : 0;
      const int ko2 = (term == 1) ? 256 : 0;
      #pragma unroll
      for (int ks = 0; ks < 4; ++ks) {
        const int ia = (qo + ks * 64 + fk) ^ swr;
        const int ib = (ko2 + ks * 64 + fk) ^ swr;
        bf16x8 a0 = *(const bf16x8*)((const char*)Qs + (wm * 32 + fr) * 512 + ia);
        bf16x8 a1 = *(const bf16x8*)((const char*)Qs + (wm * 32 + 16 + fr) * 512 + ia);
        bf16x8 b0 = *(const bf16x8*)((const char*)Ks + (wn * 32 + fr) * 512 + ib);
        bf16x8 b1 = *(const bf16x8*)((const char*)Ks + (wn * 32 + 16 + fr) * 512 + ib);
        acc_s[0][0] = MFMA16(a0, b0, acc_s[0][0]);
        acc_s[0][1] = MFMA16(a0, b1, acc_s[0][1]);
        acc_s[1][0] = MFMA16(a1, b0, acc_s[1][0]);
        acc_s[1][1] = MFMA16(a1, b1, acc_s[1][1]);
      }
    }
    #pragma unroll
    for (int mi = 0; mi < 2; ++mi)
      #pragma unroll
      for (int ni = 0; ni < 2; ++ni)
        #pragma unroll
        for (int j = 0; j < 4; ++j)
          SP[(wm * 32 + mi * 16 + crow + j) * 66 + wn * 32 + ni * 16 + ccol] =
              acc_s[mi][ni][j];
    __syncthreads();

    float s[16];
    #pragma unroll
    for (int j = 0; j < 16; ++j) s[j] = SP[sr * 66 + so * 16 + j];
    __syncthreads();

    {
      if (kt == qt) {
        #pragma unroll
        for (int j = 0; j < 16; ++j)
          if (so * 16 + j > sr) s[j] = -INFINITY;
      }
      float mx = -INFINITY;
      #pragma unroll
      for (int j = 0; j < 16; ++j) mx = fmaxf(mx, s[j]);
      mx = fmaxf(mx, __shfl_xor(mx, 1, 64));
      mx = fmaxf(mx, __shfl_xor(mx, 2, 64));
      float mnew = fmaxf(m_run, mx);
      float corr = __expf(m_run - mnew);
      float p[16];
      float ls = 0.f;
      #pragma unroll
      for (int j = 0; j < 16; ++j) { p[j] = __expf(s[j] - mnew); ls += p[j]; }
      ls += __shfl_xor(ls, 1, 64);
      ls += __shfl_xor(ls, 2, 64);
      l_run = l_run * corr + ls;
      m_run = mnew;
      char* prow = (char*)SP + sr * 256;
      const int swp = (sr & 7) << 4;
      #pragma unroll
      for (int half = 0; half < 2; ++half) {
        ushort8v vh, vl;
        #pragma unroll
        for (int j = 0; j < 8; ++j) {
          float pv = p[half * 8 + j];
          ushort hh = bf16_rn(pv);
          vh[j] = hh;
          vl[j] = bf16_rn(pv - bf16_tof(hh));
        }
        const int cb = (so * 32 + half * 16) ^ swp;
        *(ushort8v*)(prow + cb)       = vh;
        *(ushort8v*)(prow + 128 + cb) = vl;
      }
      if (so == 0) cf[sr] = corr;
    }
    __syncthreads();

    {
      float cl[8];
      #pragma unroll
      for (int mi = 0; mi < 2; ++mi)
        #pragma unroll
        for (int j = 0; j < 4; ++j)
          cl[mi * 4 + j] = cf[wm * 32 + mi * 16 + crow + j];
      #pragma unroll
      for (int mi = 0; mi < 2; ++mi)
        #pragma unroll
        for (int ni = 0; ni < 4; ++ni)
          #pragma unroll
          for (int j = 0; j < 4; ++j)
            acc_o[mi][ni][j] *= cl[mi * 4 + j];
      #pragma unroll
      for (int term = 0; term < 3; ++term) {
        const int po = (term == 2) ? 128 : 0;
        const int vo = (term == 1) ? 128 : 0;
        #pragma unroll
        for (int ks = 0; ks < 2; ++ks) {
          const int ip = (ks * 64 + fk) ^ swr;
          bf16x8 pa0 = *(const bf16x8*)((const char*)SP + (wm * 32 + fr) * 256 + po + ip);
          bf16x8 pa1 = *(const bf16x8*)((const char*)SP + (wm * 32 + 16 + fr) * 256 + po + ip);
          #pragma unroll
          for (int ni = 0; ni < 4; ++ni) {
            const int dr = vo + wn * 64 + ni * 16 + fr;
            bf16x8 vv = *(const bf16x8*)((const char*)Vs + dr * 128 + ((ks * 64 + fk) ^ swr));
            acc_o[0][ni] = MFMA16(pa0, vv, acc_o[0][ni]);
            acc_o[1][ni] = MFMA16(pa1, vv, acc_o[1][ni]);
          }
        }
      }
    }
    __syncthreads();
  }

  if (so == 0) {
    const int t = b * SEQ + qt * 64 + sr;
    cf[sr] = gate[t * NH + h] / l_run;
  }
  __syncthreads();
  {
    float rf[8];
    #pragma unroll
    for (int mi = 0; mi < 2; ++mi)
      #pragma unroll
      for (int j = 0; j < 4; ++j)
        rf[mi * 4 + j] = cf[wm * 32 + mi * 16 + crow + j];
    #pragma unroll
    for (int mi = 0; mi < 2; ++mi)
      #pragma unroll
      for (int ni = 0; ni < 4; ++ni)
        #pragma unroll
        for (int j = 0; j < 4; ++j)
          og[(size_t)(b * SEQ + qt * 64 + wm * 32 + mi * 16 + crow + j) * HID
             + h * HD + wn * 64 + ni * 16 + ccol] = acc_o[mi][ni][j] * rf[mi * 4 + j];
  }
}

extern "C" void kernel_launch(void* const* d_in, const int* in_sizes, int n_in,
                              void* d_out, int out_size, void* d_ws, size_t ws_size,
                              hipStream_t stream) {
  const float* x    = (const float*)d_in[0];
  const float* Wqkv = (const float*)d_in[1];
  const float* Wo   = (const float*)d_in[2];
  const float* gw   = (const float*)d_in[3];
  const float* gb   = (const float*)d_in[4];
  const float* nw   = (const float*)d_in[5];
  const float* cosc = (const float*)d_in[6];
  const float* sinc = (const float*)d_in[7];
  const int*   cu   = (const int*)d_in[8];
  float* out = (float*)d_out;

  float*  qkv  = (float*)d_ws;
  float*  attn = qkv + (size_t)N_TOK * QKVN;
  float*  gate = attn + (size_t)N_TOK * HID;
  ushort* Abuf = (ushort*)(gate + (size_t)N_TOK * NH);
  ushort* Bbuf = Abuf + (size_t)N_TOK * KSPLIT;
  ushort* Qsp = Abuf;
  ushort* Ksp = Bbuf;
  ushort* Vt  = Bbuf + (size_t)N_TOK * NH * 256;

  (void)hipFuncSetAttribute((const void*)gemm256,
                            hipFuncAttributeMaxDynamicSharedMemorySize, 131072);

  // 1) QKV projection (split-bf16, 256^2 deep-pipelined MFMA, K'=6144)
  split_bf16<<<2048, 256, 0, stream>>>(x,    Abuf, N_TOK * HID / 4, 1);
  split_bf16<<<2048, 256, 0, stream>>>(Wqkv, Bbuf, QKVN * HID / 4, 0);
  gemm256<<<dim3(QKVN / 256, N_TOK / 256), 512, 131072, stream>>>(
      Abuf, Bbuf, qkv, N_TOK, QKVN, KSPLIT);

  // 2) producers for MFMA attention
  rope_split<<<dim3(N_TOK * 2 * NH / 4), 256, 0, stream>>>(qkv, nw, cosc, sinc,
                                                           cu, Qsp, Ksp);
  v_split_t<<<dim3(16, 64), 256, 0, stream>>>(qkv, Vt);
  gate_kernel<<<dim3(N_TOK), 256, 0, stream>>>(x, gw, gb, gate);

  // 3) MFMA flash attention (gate fused)
  attn_mfma<<<dim3(NSEQ * NH, SEQ / 64), 256, 0, stream>>>(Qsp, Ksp, Vt, gate, attn);

  // 4) output projection (128^2 m97-structure kernel)
  split_bf16<<<2048, 256, 0, stream>>>(attn, Abuf, N_TOK * HID / 4, 1);
  split_bf16<<<2048, 256, 0, stream>>>(Wo,   Bbuf, HID * HID / 4, 0);
  gemm_bf16_nt<<<dim3(HID / 128, N_TOK / 128), 256, 0, stream>>>(
      Abuf, Bbuf, out, N_TOK, HID, KSPLIT);
}

// Round 8
// 846.674 us; speedup vs baseline: 3.1882x; 1.0343x over previous
//
#include <hip/hip_runtime.h>
#include <hip/hip_bf16.h>
#include <math.h>

#define N_TOK 4096
#define HID   2048
#define NH    16
#define HD    128
#define SEQ   1024
#define NSEQ  4
#define QKVN  (3*HID)   // 6144
#define KSPLIT (3*HID)  // split-K width: [hi|hi|lo] x [hi|lo|hi]

typedef __bf16 bf16x8 __attribute__((ext_vector_type(8)));
typedef float  f32x4  __attribute__((ext_vector_type(4)));
typedef unsigned short ushort8v __attribute__((ext_vector_type(8)));

#define MFMA16(a,b,c) __builtin_amdgcn_mfma_f32_16x16x32_bf16(a,b,c,0,0,0)

__device__ __forceinline__ ushort bf16_rn(float f) {
  unsigned u = __float_as_uint(f);
  return (ushort)((u + 0x7FFFu + ((u >> 16) & 1u)) >> 16);
}
__device__ __forceinline__ float bf16_tof(ushort h) {
  return __uint_as_float(((unsigned)h) << 16);
}
__device__ __forceinline__ void gload16(const void* g, void* l) {
  __builtin_amdgcn_global_load_lds(
      (const __attribute__((address_space(1))) void*)g,
      (__attribute__((address_space(3))) void*)l, 16, 0, 0);
}

// compiler+scheduler fence around raw barriers (rule #18/m152)
#define CFENCE asm volatile("" ::: "memory")
#define BARR do { __builtin_amdgcn_sched_barrier(0); CFENCE; \
                  __builtin_amdgcn_s_barrier(); CFENCE; \
                  __builtin_amdgcn_sched_barrier(0); } while (0)
#define VMCNT4 do { __builtin_amdgcn_sched_barrier(0); \
                    asm volatile("s_waitcnt vmcnt(4)" ::: "memory"); } while (0)
#define VMCNT3 do { __builtin_amdgcn_sched_barrier(0); \
                    asm volatile("s_waitcnt vmcnt(3)" ::: "memory"); } while (0)

// ---- split fp32 [R][2048] -> bf16 [R][6144] as [hi | X | Y] ----------------
__global__ __launch_bounds__(256)
void split_bf16(const float* __restrict__ src, ushort* __restrict__ dst,
                int total4, int amode) {
  for (int idx = blockIdx.x * 256 + threadIdx.x; idx < total4;
       idx += gridDim.x * 256) {
    const int r = idx >> 9, kq = idx & 511;
    float4 v = ((const float4*)src)[idx];
    float f[4] = {v.x, v.y, v.z, v.w};
    ushort h[4], lo[4];
    #pragma unroll
    for (int j = 0; j < 4; ++j) {
      h[j]  = bf16_rn(f[j]);
      lo[j] = bf16_rn(f[j] - bf16_tof(h[j]));
    }
    ushort4 hv = make_ushort4(h[0], h[1], h[2], h[3]);
    ushort4 lv = make_ushort4(lo[0], lo[1], lo[2], lo[3]);
    ushort* row = dst + (size_t)r * KSPLIT + kq * 4;
    *(ushort4*)(row)        = hv;
    *(ushort4*)(row + 2048) = amode ? hv : lv;
    *(ushort4*)(row + 4096) = amode ? lv : hv;
  }
}

// ---- 256x256 deep-pipelined bf16 MFMA GEMM (T1+T2+T3+T4+T5) ---------------
__global__ __launch_bounds__(512, 2)
void gemm256(const ushort* __restrict__ A, const ushort* __restrict__ B,
             float* __restrict__ C, int M, int N, int K) {
  extern __shared__ ushort lds[];
  const int nx = gridDim.x;
  const int nwg = nx * gridDim.y;
  const int bid = blockIdx.y * nx + blockIdx.x;
  const int cpx = nwg >> 3;                    // grids are %8==0
  const int swz = (bid & 7) * cpx + (bid >> 3);
  const int bx = swz % nx, by = swz / nx;
  const int m0 = by * 256, n0 = bx * 256;
  const int tid = threadIdx.x;
  const int w = tid >> 6, l = tid & 63;
  const int wm = w >> 2, wn = w & 3;
  const int fr = l & 15, kc = l >> 4;
  const int cx = (kc ^ ((fr >> 1) & 3)) * 8;       // swizzled 16B chunk (us)
  const int aoff = (wm * 128 + fr) * 32 + cx;      // A frag base (us)
  const int boff = 16384 + (wn * 64 + fr) * 32 + cx; // B frag base (us)
  const int tr0 = tid >> 2;
  const int q0c = tid & 3;
  const int wub = (tid & 448) * 8;                 // wave-uniform LDS chunk base
  const int NTILE = K >> 6;

  auto stage = [&](int bufus, int kt, int s) {
    const int koe = kt * 64 + s * 32;
    #pragma unroll
    for (int i = 0; i < 2; ++i) {
      const int tr = i * 128 + tr0;
      const int gq = (q0c ^ ((tr >> 1) & 3)) * 8;
      gload16(A + (size_t)(m0 + tr) * K + koe + gq,
              &lds[bufus + s * 8192 + i * 4096 + wub]);
    }
    #pragma unroll
    for (int i = 0; i < 2; ++i) {
      const int tr = i * 128 + tr0;
      const int gq = (q0c ^ ((tr >> 1) & 3)) * 8;
      gload16(B + (size_t)(n0 + tr) * K + koe + gq,
              &lds[bufus + 16384 + s * 8192 + i * 4096 + wub]);
    }
  };
  auto lda4 = [&](bf16x8* dst, int cb, int s, int mbase) {
    #pragma unroll
    for (int m = 0; m < 4; ++m)
      dst[m] = *(const bf16x8*)&lds[cb + s * 8192 + aoff + (mbase + m) * 512];
  };
  auto ldb4 = [&](bf16x8* dst, int cb, int s) {
    #pragma unroll
    for (int n = 0; n < 4; ++n)
      dst[n] = *(const bf16x8*)&lds[cb + s * 8192 + boff + n * 512];
  };

  f32x4 acc[8][4];
  #pragma unroll
  for (int m = 0; m < 8; ++m)
    #pragma unroll
    for (int n = 0; n < 4; ++n)
      acc[m][n] = (f32x4){0.f, 0.f, 0.f, 0.f};

  auto mm = [&](bf16x8* av_, bf16x8* bv_, int mbase) {
    __builtin_amdgcn_s_setprio(1);
    #pragma unroll
    for (int m = 0; m < 4; ++m)
      #pragma unroll
      for (int n = 0; n < 4; ++n)
        acc[mbase + m][n] = MFMA16(av_[m], bv_[n], acc[mbase + m][n]);
    __builtin_amdgcn_s_setprio(0);
  };

  stage(0, 0, 0);
  stage(0, 0, 1);
  VMCNT4;
  BARR;

  for (int T = 0; T < NTILE; ++T) {
    const int cb = (T & 1) << 15;
    const int nb = 32768 - cb;
    const bool st = (T + 1) < NTILE;
    bf16x8 a0[4], b0[4], a1[4];
    lda4(a0, cb, 0, 0);
    ldb4(b0, cb, 0);
    if (st) stage(nb, T + 1, 0);
    BARR;
    mm(a0, b0, 0);
    BARR;
    lda4(a1, cb, 0, 4);
    VMCNT4;
    BARR;
    mm(a1, b0, 4);
    BARR;
    lda4(a0, cb, 1, 0);
    ldb4(b0, cb, 1);
    if (st) stage(nb, T + 1, 1);
    BARR;
    mm(a0, b0, 0);
    BARR;
    lda4(a1, cb, 1, 4);
    VMCNT4;
    BARR;
    mm(a1, b0, 4);
    BARR;
  }

  const int crow = (l >> 4) * 4, ccol = l & 15;
  #pragma unroll
  for (int m = 0; m < 8; ++m)
    #pragma unroll
    for (int n = 0; n < 4; ++n) {
      #pragma unroll
      for (int j = 0; j < 4; ++j)
        C[(size_t)(m0 + wm * 128 + m * 16 + crow + j) * N +
          (n0 + wn * 64 + n * 16 + ccol)] = acc[m][n][j];
    }
}

// ---- 256x128 deep-pipelined variant (balanced out-proj grid) --------------
// 8 waves as 4M x 2N, per-wave C = 64x64. LDS 96 KB: per buf A 32K + B 16K.
// stage = 3 gloads -> counted vmcnt(3), same ledger as gemm256.
__global__ __launch_bounds__(512, 2)
void gemm256_bn128(const ushort* __restrict__ A, const ushort* __restrict__ B,
                   float* __restrict__ C, int M, int N, int K) {
  extern __shared__ ushort lds[];
  const int nx = gridDim.x;
  const int nwg = nx * gridDim.y;
  const int bid = blockIdx.y * nx + blockIdx.x;
  const int cpx = nwg >> 3;
  const int swz = (bid & 7) * cpx + (bid >> 3);
  const int bx = swz % nx, by = swz / nx;
  const int m0 = by * 256, n0 = bx * 128;
  const int tid = threadIdx.x;
  const int w = tid >> 6, l = tid & 63;
  const int wm = w >> 1, wn = w & 1;              // 4M x 2N
  const int fr = l & 15, kc = l >> 4;
  const int cx = (kc ^ ((fr >> 1) & 3)) * 8;
  const int aoff = (wm * 64 + fr) * 32 + cx;      // A region (rows 0..255)
  const int tr0 = tid >> 2;
  const int q0c = tid & 3;
  const int wub = (tid & 448) * 8;
  const int NTILE = K >> 6;

  // buf stride 24576 us (48KB): A at [0,16384) (s*8192), B at [16384,24576) (s*4096)
  auto stage = [&](int bufus, int kt, int s) {
    const int koe = kt * 64 + s * 32;
    #pragma unroll
    for (int i = 0; i < 2; ++i) {
      const int tr = i * 128 + tr0;
      const int gq = (q0c ^ ((tr >> 1) & 3)) * 8;
      gload16(A + (size_t)(m0 + tr) * K + koe + gq,
              &lds[bufus + s * 8192 + i * 4096 + wub]);
    }
    {
      const int tr = tr0;
      const int gq = (q0c ^ ((tr >> 1) & 3)) * 8;
      gload16(B + (size_t)(n0 + tr) * K + koe + gq,
              &lds[bufus + 16384 + s * 4096 + wub]);
    }
  };
  auto lda2 = [&](bf16x8* dst, int cb, int s, int mbase) {
    #pragma unroll
    for (int m = 0; m < 2; ++m)
      dst[m] = *(const bf16x8*)&lds[cb + s * 8192 + aoff + (mbase + m) * 512];
  };
  // FIX (R6): B region base is cb + 16384 + s*4096; previous version added
  // the 16384 twice via boff and read buffer-1's A region -> absmax 33.
  auto ldb4 = [&](bf16x8* dst, int cb, int s) {
    #pragma unroll
    for (int n = 0; n < 4; ++n)
      dst[n] = *(const bf16x8*)&lds[cb + 16384 + s * 4096 +
                                    (wn * 64 + n * 16 + fr) * 32 + cx];
  };

  f32x4 acc[4][4];
  #pragma unroll
  for (int m = 0; m < 4; ++m)
    #pragma unroll
    for (int n = 0; n < 4; ++n)
      acc[m][n] = (f32x4){0.f, 0.f, 0.f, 0.f};

  auto mm = [&](bf16x8* av_, bf16x8* bv_, int mbase) {
    __builtin_amdgcn_s_setprio(1);
    #pragma unroll
    for (int m = 0; m < 2; ++m)
      #pragma unroll
      for (int n = 0; n < 4; ++n)
        acc[mbase + m][n] = MFMA16(av_[m], bv_[n], acc[mbase + m][n]);
    __builtin_amdgcn_s_setprio(0);
  };

  stage(0, 0, 0);
  stage(0, 0, 1);
  VMCNT3;
  BARR;

  for (int T = 0; T < NTILE; ++T) {
    const int cb = (T & 1) ? 24576 : 0;
    const int nb = 24576 - cb;
    const bool st = (T + 1) < NTILE;
    bf16x8 a0[2], b0[4], a1[2];
    lda2(a0, cb, 0, 0);
    ldb4(b0, cb, 0);
    if (st) stage(nb, T + 1, 0);
    BARR;
    mm(a0, b0, 0);
    BARR;
    lda2(a1, cb, 0, 2);
    VMCNT3;
    BARR;
    mm(a1, b0, 2);
    BARR;
    lda2(a0, cb, 1, 0);
    ldb4(b0, cb, 1);
    if (st) stage(nb, T + 1, 1);
    BARR;
    mm(a0, b0, 0);
    BARR;
    lda2(a1, cb, 1, 2);
    VMCNT3;
    BARR;
    mm(a1, b0, 2);
    BARR;
  }

  const int crow = (l >> 4) * 4, ccol = l & 15;
  #pragma unroll
  for (int m = 0; m < 4; ++m)
    #pragma unroll
    for (int n = 0; n < 4; ++n) {
      #pragma unroll
      for (int j = 0; j < 4; ++j)
        C[(size_t)(m0 + wm * 64 + m * 16 + crow + j) * N +
          (n0 + wn * 64 + n * 16 + ccol)] = acc[m][n][j];
    }
}

// ---- RoPE + RMSNorm -> swizzled split-bf16 Qsp/Ksp -------------------------
__global__ __launch_bounds__(256)
void rope_split(const float* __restrict__ qkv, const float* __restrict__ norm_w,
                const float* __restrict__ cosc, const float* __restrict__ sinc,
                const int* __restrict__ cu,
                ushort* __restrict__ Qsp, ushort* __restrict__ Ksp) {
  const int wid  = blockIdx.x * 4 + (threadIdx.x >> 6);
  const int lane = threadIdx.x & 63;
  const int t   = wid >> 5;
  const int rem = wid & 31;
  const int s   = rem >> 4;
  const int h   = rem & 15;
  const int pos = t - cu[t >> 10];
  const float* p = qkv + (size_t)t * QKVN + s * HID + h * HD;
  float x1 = p[lane], x2 = p[lane + 64];
  float c  = cosc[pos * 64 + lane];
  float sn = sinc[pos * 64 + lane];
  float y1 = x1 * c + x2 * sn;
  float y2 = x2 * c - x1 * sn;
  float ss = y1 * y1 + y2 * y2;
  #pragma unroll
  for (int o = 32; o > 0; o >>= 1) ss += __shfl_xor(ss, o, 64);
  float r = rsqrtf(ss * (1.0f / 128.0f) + 1e-6f);
  const float sc = s ? 1.0f : 0.08838834764831845f;
  float o1 = y1 * r * norm_w[lane] * sc;
  float o2 = y2 * r * norm_w[lane + 64] * sc;
  ushort h1 = bf16_rn(o1), l1 = bf16_rn(o1 - bf16_tof(h1));
  ushort h2 = bf16_rn(o2), l2 = bf16_rn(o2 - bf16_tof(h2));
  char* db = (char*)((s ? Ksp : Qsp) + ((size_t)t * NH + h) * 256);
  const int b0 = (lane * 2) ^ ((t & 7) << 4);
  *(ushort*)(db + b0)       = h1;
  *(ushort*)(db + 128 + b0) = h2;
  *(ushort*)(db + 256 + b0) = l1;
  *(ushort*)(db + 384 + b0) = l2;
}

// ---- V transpose+split -----------------------------------------------------
__global__ __launch_bounds__(256)
void v_split_t(const float* __restrict__ qkv, ushort* __restrict__ Vt) {
  __shared__ float Vb[64][133];
  const int kt = blockIdx.x, bh = blockIdx.y;
  const int b = bh >> 4, h = bh & 15;
  const int tid = threadIdx.x;
  {
    const int k = tid >> 5, dm = (tid & 31) * 4;
    const float* src = qkv + (size_t)(b * SEQ + kt * 64) * QKVN + 2 * HID + h * HD;
    #pragma unroll
    for (int i = 0; i < 8; ++i) {
      float4 v = *(const float4*)(src + (size_t)(i * 8 + k) * QKVN + dm);
      Vb[i * 8 + k][dm]     = v.x;
      Vb[i * 8 + k][dm + 1] = v.y;
      Vb[i * 8 + k][dm + 2] = v.z;
      Vb[i * 8 + k][dm + 3] = v.w;
    }
  }
  __syncthreads();
  const int c  = tid & 7;
  const int d0 = tid >> 3;
  char* base = (char*)Vt + (size_t)bh * 256 * 2048;
  #pragma unroll
  for (int it = 0; it < 4; ++it) {
    const int d = d0 + it * 32;
    ushort8v vh, vl;
    #pragma unroll
    for (int j = 0; j < 8; ++j) {
      float f = Vb[c * 8 + j][d];
      ushort hh = bf16_rn(f);
      vh[j] = hh;
      vl[j] = bf16_rn(f - bf16_tof(hh));
    }
    const int cc = (c ^ (d & 7)) * 16;
    *(ushort8v*)(base + (size_t)d * 2048 + kt * 128 + cc)        = vh;
    *(ushort8v*)(base + (size_t)(128 + d) * 2048 + kt * 128 + cc) = vl;
  }
}

// ---- gate = sigmoid(x @ gate_w^T + gate_b) ---------------------------------
__global__ __launch_bounds__(256)
void gate_kernel(const float* __restrict__ x, const float* __restrict__ gw,
                 const float* __restrict__ gb, float* __restrict__ gate) {
  __shared__ float xs[HID];
  const int t = blockIdx.x, tid = threadIdx.x;
  *(float4*)&xs[tid * 8]     = *(const float4*)&x[(size_t)t * HID + tid * 8];
  *(float4*)&xs[tid * 8 + 4] = *(const float4*)&x[(size_t)t * HID + tid * 8 + 4];
  __syncthreads();
  const int h = tid >> 4, i = tid & 15;
  const float* w  = gw + (size_t)h * HID + i * 128;
  const float* xx = xs + i * 128;
  float sum = 0.f;
  #pragma unroll
  for (int j = 0; j < 128; j += 4) {
    float4 wv = *(const float4*)(w + j);
    float4 xv = *(const float4*)(xx + j);
    sum += wv.x * xv.x + wv.y * xv.y + wv.z * xv.z + wv.w * xv.w;
  }
  sum += __shfl_xor(sum, 8, 64);
  sum += __shfl_xor(sum, 4, 64);
  sum += __shfl_xor(sum, 2, 64);
  sum += __shfl_xor(sum, 1, 64);
  if (i == 0) gate[t * NH + h] = 1.f / (1.f + __expf(-(sum + gb[h])));
}

// ---- MFMA flash attention; epilogue writes split-bf16 A-operand directly ---
__global__ __launch_bounds__(256, 1)
void attn_mfma(const ushort* __restrict__ Qsp, const ushort* __restrict__ Ksp,
               const ushort* __restrict__ Vtg, const float* __restrict__ gate,
               ushort* __restrict__ Aout) {
  __shared__ ushort Qs[64 * 256];
  __shared__ ushort Ks[64 * 256];
  __shared__ ushort Vs[256 * 64];
  __shared__ float  SP[64 * 66];
  __shared__ float  cf[64];
  const int bh = blockIdx.x, b = bh >> 4, h = bh & 15;
  const int qt = (int)gridDim.y - 1 - (int)blockIdx.y;
  const int tid = threadIdx.x;
  const int w = tid >> 6, l = tid & 63;
  const int wm = w >> 1, wn = w & 1;
  const int fr = l & 15;
  const int fk = (l >> 4) * 16;
  const int swr = (fr & 7) << 4;
  const int crow = (l >> 4) * 4, ccol = l & 15;
  const int sr = tid >> 2, so = tid & 3;

  {
    const char* qg = (const char*)Qsp + ((size_t)(b * SEQ + qt * 64) * 16 + h) * 512
                     + (size_t)w * 131072 + (size_t)(l >> 5) * 8192 + (l & 31) * 16;
    char* qd = (char*)Qs + w * 8192;
    #pragma unroll
    for (int i = 0; i < 8; ++i) gload16(qg + i * 16384, qd + i * 1024);
  }
  const char* kg = (const char*)Ksp + ((size_t)(b * SEQ) * 16 + h) * 512
                   + (size_t)w * 131072 + (size_t)(l >> 5) * 8192 + (l & 31) * 16;
  const char* vg = (const char*)Vtg + ((size_t)bh * 256 + w * 64 + (l >> 3)) * 2048
                   + (l & 7) * 16;
  char* kd = (char*)Ks + w * 8192;
  char* vd = (char*)Vs + w * 8192;

  f32x4 acc_o[2][4];
  #pragma unroll
  for (int mi = 0; mi < 2; ++mi)
    #pragma unroll
    for (int ni = 0; ni < 4; ++ni)
      acc_o[mi][ni] = (f32x4){0.f, 0.f, 0.f, 0.f};
  float m_run = -INFINITY, l_run = 0.f;

  for (int kt = 0; kt <= qt; ++kt) {
    #pragma unroll
    for (int i = 0; i < 8; ++i) gload16(kg + i * 16384, kd + i * 1024);
    #pragma unroll
    for (int i = 0; i < 8; ++i) gload16(vg + i * 16384, vd + i * 1024);
    kg += 524288;
    vg += 128;
    __syncthreads();

    f32x4 acc_s[2][2];
    #pragma unroll
    for (int mi = 0; mi < 2; ++mi)
      #pragma unroll
      for (int ni = 0; ni < 2; ++ni)
        acc_s[mi][ni] = (f32x4){0.f, 0.f, 0.f, 0.f};
    #pragma unroll
    for (int term = 0; term < 3; ++term) {
      const int qo = (term == 2) ? 256 : 0;
      const int ko2 = (term == 1) ? 256 : 0;
      #pragma unroll
      for (int ks = 0; ks < 4; ++ks) {
        const int ia = (qo + ks * 64 + fk) ^ swr;
        const int ib = (ko2 + ks * 64 + fk) ^ swr;
        bf16x8 a0 = *(const bf16x8*)((const char*)Qs + (wm * 32 + fr) * 512 + ia);
        bf16x8 a1 = *(const bf16x8*)((const char*)Qs + (wm * 32 + 16 + fr) * 512 + ia);
        bf16x8 b0 = *(const bf16x8*)((const char*)Ks + (wn * 32 + fr) * 512 + ib);
        bf16x8 b1 = *(const bf16x8*)((const char*)Ks + (wn * 32 + 16 + fr) * 512 + ib);
        acc_s[0][0] = MFMA16(a0, b0, acc_s[0][0]);
        acc_s[0][1] = MFMA16(a0, b1, acc_s[0][1]);
        acc_s[1][0] = MFMA16(a1, b0, acc_s[1][0]);
        acc_s[1][1] = MFMA16(a1, b1, acc_s[1][1]);
      }
    }
    #pragma unroll
    for (int mi = 0; mi < 2; ++mi)
      #pragma unroll
      for (int ni = 0; ni < 2; ++ni)
        #pragma unroll
        for (int j = 0; j < 4; ++j)
          SP[(wm * 32 + mi * 16 + crow + j) * 66 + wn * 32 + ni * 16 + ccol] =
              acc_s[mi][ni][j];
    __syncthreads();

    float s[16];
    #pragma unroll
    for (int j = 0; j < 16; ++j) s[j] = SP[sr * 66 + so * 16 + j];
    __syncthreads();

    {
      if (kt == qt) {
        #pragma unroll
        for (int j = 0; j < 16; ++j)
          if (so * 16 + j > sr) s[j] = -INFINITY;
      }
      float mx = -INFINITY;
      #pragma unroll
      for (int j = 0; j < 16; ++j) mx = fmaxf(mx, s[j]);
      mx = fmaxf(mx, __shfl_xor(mx, 1, 64));
      mx = fmaxf(mx, __shfl_xor(mx, 2, 64));
      float mnew = fmaxf(m_run, mx);
      float corr = __expf(m_run - mnew);
      float p[16];
      float ls = 0.f;
      #pragma unroll
      for (int j = 0; j < 16; ++j) { p[j] = __expf(s[j] - mnew); ls += p[j]; }
      ls += __shfl_xor(ls, 1, 64);
      ls += __shfl_xor(ls, 2, 64);
      l_run = l_run * corr + ls;
      m_run = mnew;
      char* prow = (char*)SP + sr * 256;
      const int swp = (sr & 7) << 4;
      #pragma unroll
      for (int half = 0; half < 2; ++half) {
        ushort8v vh, vl;
        #pragma unroll
        for (int j = 0; j < 8; ++j) {
          float pv = p[half * 8 + j];
          ushort hh = bf16_rn(pv);
          vh[j] = hh;
          vl[j] = bf16_rn(pv - bf16_tof(hh));
        }
        const int cb = (so * 32 + half * 16) ^ swp;
        *(ushort8v*)(prow + cb)       = vh;
        *(ushort8v*)(prow + 128 + cb) = vl;
      }
      if (so == 0) cf[sr] = corr;
    }
    __syncthreads();

    {
      float cl[8];
      #pragma unroll
      for (int mi = 0; mi < 2; ++mi)
        #pragma unroll
        for (int j = 0; j < 4; ++j)
          cl[mi * 4 + j] = cf[wm * 32 + mi * 16 + crow + j];
      #pragma unroll
      for (int mi = 0; mi < 2; ++mi)
        #pragma unroll
        for (int ni = 0; ni < 4; ++ni)
          #pragma unroll
          for (int j = 0; j < 4; ++j)
            acc_o[mi][ni][j] *= cl[mi * 4 + j];
      #pragma unroll
      for (int term = 0; term < 3; ++term) {
        const int po = (term == 2) ? 128 : 0;
        const int vo = (term == 1) ? 128 : 0;
        #pragma unroll
        for (int ks = 0; ks < 2; ++ks) {
          const int ip = (ks * 64 + fk) ^ swr;
          bf16x8 pa0 = *(const bf16x8*)((const char*)SP + (wm * 32 + fr) * 256 + po + ip);
          bf16x8 pa1 = *(const bf16x8*)((const char*)SP + (wm * 32 + 16 + fr) * 256 + po + ip);
          #pragma unroll
          for (int ni = 0; ni < 4; ++ni) {
            const int dr = vo + wn * 64 + ni * 16 + fr;
            bf16x8 vv = *(const bf16x8*)((const char*)Vs + dr * 128 + ((ks * 64 + fk) ^ swr));
            acc_o[0][ni] = MFMA16(pa0, vv, acc_o[0][ni]);
            acc_o[1][ni] = MFMA16(pa1, vv, acc_o[1][ni]);
          }
        }
      }
    }
    __syncthreads();
  }

  if (so == 0) {
    const int t = b * SEQ + qt * 64 + sr;
    cf[sr] = gate[t * NH + h] / l_run;
  }
  __syncthreads();
  {
    float rf[8];
    #pragma unroll
    for (int mi = 0; mi < 2; ++mi)
      #pragma unroll
      for (int j = 0; j < 4; ++j)
        rf[mi * 4 + j] = cf[wm * 32 + mi * 16 + crow + j];
    // write split-bf16 A-operand rows [hi | hi | lo] directly
    #pragma unroll
    for (int mi = 0; mi < 2; ++mi)
      #pragma unroll
      for (int j = 0; j < 4; ++j) {
        const int trow = b * SEQ + qt * 64 + wm * 32 + mi * 16 + crow + j;
        ushort* rp = Aout + (size_t)trow * KSPLIT;
        const float rfv = rf[mi * 4 + j];
        #pragma unroll
        for (int ni = 0; ni < 4; ++ni) {
          const float v = acc_o[mi][ni][j] * rfv;
          const ushort hh = bf16_rn(v);
          const ushort ll = bf16_rn(v - bf16_tof(hh));
          const int col = h * HD + wn * 64 + ni * 16 + ccol;
          rp[col]        = hh;
          rp[col + 2048] = hh;
          rp[col + 4096] = ll;
        }
      }
  }
}

extern "C" void kernel_launch(void* const* d_in, const int* in_sizes, int n_in,
                              void* d_out, int out_size, void* d_ws, size_t ws_size,
                              hipStream_t stream) {
  const float* x    = (const float*)d_in[0];
  const float* Wqkv = (const float*)d_in[1];
  const float* Wo   = (const float*)d_in[2];
  const float* gw   = (const float*)d_in[3];
  const float* gb   = (const float*)d_in[4];
  const float* nw   = (const float*)d_in[5];
  const float* cosc = (const float*)d_in[6];
  const float* sinc = (const float*)d_in[7];
  const int*   cu   = (const int*)d_in[8];
  float* out = (float*)d_out;

  // workspace layout (260 MB total, no live aliases):
  float*  qkv  = (float*)d_ws;                              // [4096][6144] f32
  ushort* Qsp  = (ushort*)(qkv + (size_t)N_TOK * QKVN);     // [4096][16][256]
  float*  gate = (float*)(Qsp + (size_t)N_TOK * NH * 256);  // [4096][16]
  ushort* Abuf = (ushort*)(gate + (size_t)N_TOK * NH);      // [4096][6144] bf16
  ushort* Bbuf = Abuf + (size_t)N_TOK * KSPLIT;             // 75.5 MB region
  ushort* Ksp  = Bbuf;                                      // alias (Wqkv-split dead)
  ushort* Vt   = Bbuf + (size_t)N_TOK * NH * 256;           // alias

  (void)hipFuncSetAttribute((const void*)gemm256,
                            hipFuncAttributeMaxDynamicSharedMemorySize, 131072);
  (void)hipFuncSetAttribute((const void*)gemm256_bn128,
                            hipFuncAttributeMaxDynamicSharedMemorySize, 98304);

  // 1) QKV projection (split-bf16, 256^2 deep-pipelined MFMA, K'=6144)
  split_bf16<<<2048, 256, 0, stream>>>(x,    Abuf, N_TOK * HID / 4, 1);
  split_bf16<<<2048, 256, 0, stream>>>(Wqkv, Bbuf, QKVN * HID / 4, 0);
  gemm256<<<dim3(QKVN / 256, N_TOK / 256), 512, 131072, stream>>>(
      Abuf, Bbuf, qkv, N_TOK, QKVN, KSPLIT);

  // 2) producers for MFMA attention
  rope_split<<<dim3(N_TOK * 2 * NH / 4), 256, 0, stream>>>(qkv, nw, cosc, sinc,
                                                           cu, Qsp, Ksp);
  v_split_t<<<dim3(16, 64), 256, 0, stream>>>(qkv, Vt);
  gate_kernel<<<dim3(N_TOK), 256, 0, stream>>>(x, gw, gb, gate);

  // 3) MFMA flash attention; epilogue emits out-proj A-operand (split) to Abuf
  attn_mfma<<<dim3(NSEQ * NH, SEQ / 64), 256, 0, stream>>>(Qsp, Ksp, Vt, gate, Abuf);

  // 4) output projection (balanced 256x128 deep-pipelined MFMA)
  split_bf16<<<2048, 256, 0, stream>>>(Wo, Bbuf, HID * HID / 4, 0);
  gemm256_bn128<<<dim3(HID / 128, N_TOK / 256), 512, 98304, stream>>>(
      Abuf, Bbuf, out, N_TOK, HID, KSPLIT);
}